// Round 1
// baseline (110898.303 us; speedup 1.0000x reference)
//
#include <hip/hip_runtime.h>
#include <cmath>

#define NWG 256
#define NT  256

// ---------------- workspace layout (float offsets) ----------------
static constexpr size_t BAR_  = 0;                               // barrier counters (uint area, 1024 floats)
static constexpr size_t XT_   = 1024;                            // xT[t][k][b]      512*64*64
static constexpr size_t H1T_  = XT_   + (size_t)512*64*64;       // H1T[t][k][b]     512*512*64
static constexpr size_t ENC_  = H1T_  + (size_t)512*512*64;      // ENC[b][k][s]     64*512*512
static constexpr size_t HST_  = ENC_  + (size_t)64*512*512;      // HST[d][buf][j][b] 2*2*256*64
static constexpr size_t CST_  = HST_  + (size_t)2*2*256*64;      // CST[k][b]        512*64
static constexpr size_t HDT_  = CST_  + (size_t)512*64;          // hdT[buf][k][b]   2*512*64
static constexpr size_t CTXT_ = HDT_  + (size_t)2*512*64;        // ctxT[k][b]       1024*64
static constexpr size_t PARTH_= CTXT_ + (size_t)1024*64;         // partH[b][sblk][k] 64*16*512
static constexpr size_t PARTC_= PARTH_+ (size_t)64*16*512;
static constexpr size_t PMZ_  = PARTC_+ (size_t)64*16*512;       // [hc][b][sblk][2]  2*64*16*2
static constexpr size_t WS_END= PMZ_  + 4096;                    // 36,934,656 floats ~141MB

// ---------------- LDS layout (float offsets) ----------------
static constexpr int WL_O   = 0;              // weights [k][8 slots]   12800 (dec K=1600)
static constexpr int SLAB_O = 12800;          // enc slab [512][36]     18432
static constexpr int RED_O  = SLAB_O + 18432; // partials [4][8][64]     2048
static constexpr int HB_O   = RED_O  + 2048;  // dec h_b[512]
static constexpr int CB_O   = HB_O   + 512;   // dec c_b[512]
static constexpr int WH_O   = CB_O   + 512;   // softmax wts h [32]
static constexpr int WC_O   = WH_O   + 32;    // softmax wts c [32]
static constexpr int BI_O   = WC_O   + 32;    // bias [8]
static constexpr int SMEM_F = BI_O   + 8;     // 34376 floats = 137504 B

__device__ __forceinline__ float sigm(float v) { return 1.f / (1.f + expf(-v)); }

// Device-scope tree grid-barrier: 8 leaves x 32 WGs, sense-reversing generation.
__device__ __forceinline__ void gridbar(unsigned* bar) {
  __syncthreads();
  if (threadIdx.x == 0) {
    __threadfence();                                   // publish this WG's global writes
    unsigned* gen  = bar;                              // [0]
    unsigned* root = bar + 32;                         // separate cacheline
    unsigned* leaf = bar + 64 + (blockIdx.x & 7) * 32;
    unsigned g = __hip_atomic_load(gen, __ATOMIC_RELAXED, __HIP_MEMORY_SCOPE_AGENT);
    unsigned o = __hip_atomic_fetch_add(leaf, 1u, __ATOMIC_ACQ_REL, __HIP_MEMORY_SCOPE_AGENT);
    if (o == 31u) {
      __hip_atomic_store(leaf, 0u, __ATOMIC_RELAXED, __HIP_MEMORY_SCOPE_AGENT);
      unsigned r = __hip_atomic_fetch_add(root, 1u, __ATOMIC_ACQ_REL, __HIP_MEMORY_SCOPE_AGENT);
      if (r == 7u) {
        __hip_atomic_store(root, 0u, __ATOMIC_RELAXED, __HIP_MEMORY_SCOPE_AGENT);
        __hip_atomic_fetch_add(gen, 1u, __ATOMIC_RELEASE, __HIP_MEMORY_SCOPE_AGENT);
      }
    }
    while (__hip_atomic_load(gen, __ATOMIC_ACQUIRE, __HIP_MEMORY_SCOPE_AGENT) == g)
      __builtin_amdgcn_s_sleep(8);
  }
  __syncthreads();
}

// One K-segment of the gate GEMM. Lane tile: 4 rows (slots rq*4..rq*4+3) x 2 batches (2bq,2bq+1).
// kb: global, [k][64] activation stream. wl: LDS, [k][8].
template<int N>
__device__ __forceinline__ void dot_seg(float (&acc)[4][2], const float* kb,
                                        const float* wl, int rq, int bq) {
#pragma unroll 4
  for (int i = 0; i < N; ++i) {
    float2 hv = *(const float2*)(kb + (size_t)i * 64 + 2 * bq);
    float4 wv = *(const float4*)(wl + i * 8 + rq * 4);
    acc[0][0] = fmaf(wv.x, hv.x, acc[0][0]); acc[0][1] = fmaf(wv.x, hv.y, acc[0][1]);
    acc[1][0] = fmaf(wv.y, hv.x, acc[1][0]); acc[1][1] = fmaf(wv.y, hv.y, acc[1][1]);
    acc[2][0] = fmaf(wv.z, hv.x, acc[2][0]); acc[2][1] = fmaf(wv.z, hv.y, acc[2][1]);
    acc[3][0] = fmaf(wv.w, hv.x, acc[3][0]); acc[3][1] = fmaf(wv.w, hv.y, acc[3][1]);
  }
}

// Load this WG's 8 gate rows (2 units x 4 gates, slot = g*2+u) into LDS, plus bias.
__device__ void fill_wl(float* WLs, float* BIs,
                        const float* Wih, const float* Whh,
                        const float* bih, const float* bhh,
                        int KI, int KH, int gstride, int u0, int K) {
  for (int idx = threadIdx.x; idx < K * 8; idx += NT) {
    int k = idx >> 3, slot = idx & 7;
    int row = (slot >> 1) * gstride + u0 + (slot & 1);
    WLs[k * 8 + slot] = (k < KI) ? Wih[(size_t)row * KI + k]
                                 : Whh[(size_t)row * KH + (k - KI)];
  }
  if (threadIdx.x < 8) {
    int row = ((int)threadIdx.x >> 1) * gstride + u0 + ((int)threadIdx.x & 1);
    BIs[threadIdx.x] = bih[row] + bhh[row];
  }
  __syncthreads();
}

extern "C" __global__ void __launch_bounds__(NT, 1)
seq2seq_ker(const float* __restrict__ x,
            const float* __restrict__ Wih0, const float* __restrict__ Whh0,
            const float* __restrict__ bih0, const float* __restrict__ bhh0,
            const float* __restrict__ Wih1, const float* __restrict__ Whh1,
            const float* __restrict__ bih1, const float* __restrict__ bhh1,
            const float* __restrict__ Wihd, const float* __restrict__ Whhd,
            const float* __restrict__ bihd, const float* __restrict__ bhhd,
            const float* __restrict__ Wp,   const float* __restrict__ bp,
            float* out, float* ws) {
  extern __shared__ float smem[];
  float* WLs   = smem + WL_O;
  float* SLABs = smem + SLAB_O;
  float* REDs  = smem + RED_O;
  float* HBs   = smem + HB_O;
  float* CBs   = smem + CB_O;
  float* WHs   = smem + WH_O;
  float* WCs   = smem + WC_O;
  float* BIs   = smem + BI_O;

  unsigned* bar = (unsigned*)ws;
  const int tid  = threadIdx.x;
  const int wg   = blockIdx.x;
  const int gtid = wg * NT + tid;
  const int lane = tid & 63, q = tid >> 6;
  const int rq = lane & 1, bq = lane >> 1;

  // ---------- prep: transpose x -> xT[t][k][b]; zero h/c state ----------
  for (size_t i = gtid; i < (size_t)512 * 64 * 64; i += (size_t)NWG * NT) {
    int b = (int)(i & 63), k = (int)((i >> 6) & 63), t = (int)(i >> 12);
    ws[XT_ + i] = x[((size_t)b * 512 + t) * 64 + k];
  }
  for (size_t i = gtid; i < (size_t)(2 * 2 * 256 * 64 + 512 * 64); i += (size_t)NWG * NT)
    ws[HST_ + i] = 0.f;   // HST + CST are adjacent

  // ---------- encoder: 2 layers ----------
  const int d  = wg >> 7;            // direction
  const int u0 = (wg & 127) * 2;     // this WG's 2 hidden units

  for (int layer = 0; layer < 2; ++layer) {
    if (layer == 0)
      fill_wl(WLs, BIs, Wih0 + (size_t)d * 1024 * 64,  Whh0 + (size_t)d * 1024 * 256,
              bih0 + d * 1024, bhh0 + d * 1024, 64, 256, 256, u0, 320);
    else
      fill_wl(WLs, BIs, Wih1 + (size_t)d * 1024 * 512, Whh1 + (size_t)d * 1024 * 256,
              bih1 + d * 1024, bhh1 + d * 1024, 512, 256, 256, u0, 768);
    gridbar(bar);  // state zeroed + weights ready (zeroing for layer1 done below)

    for (int t = 0; t < 512; ++t) {
      const int cur = t & 1, nxt = cur ^ 1;
      const int tt = d ? (511 - t) : t;
      float acc[4][2] = {{0.f,0.f},{0.f,0.f},{0.f,0.f},{0.f,0.f}};
      const float* hbase = ws + HST_ + ((size_t)(d * 2 + cur) * 256) * 64;
      if (layer == 0) {
        const float* xb = ws + XT_ + (size_t)tt * 4096;
        if      (q == 0) { dot_seg<64>(acc, xb, WLs, rq, bq);
                           dot_seg<16>(acc, hbase, WLs + 64 * 8, rq, bq); }
        else if (q == 1)   dot_seg<80>(acc, hbase + 16 * 64,  WLs + 80 * 8,  rq, bq);
        else if (q == 2)   dot_seg<80>(acc, hbase + 96 * 64,  WLs + 160 * 8, rq, bq);
        else               dot_seg<80>(acc, hbase + 176 * 64, WLs + 240 * 8, rq, bq);
      } else {
        const float* ib = ws + H1T_ + (size_t)tt * 512 * 64;
        if      (q == 0)   dot_seg<192>(acc, ib,            WLs,            rq, bq);
        else if (q == 1)   dot_seg<192>(acc, ib + 192 * 64, WLs + 192 * 8,  rq, bq);
        else if (q == 2) { dot_seg<128>(acc, ib + 384 * 64, WLs + 384 * 8,  rq, bq);
                           dot_seg<64> (acc, hbase,         WLs + 512 * 8,  rq, bq); }
        else               dot_seg<192>(acc, hbase + 64*64, WLs + 576 * 8,  rq, bq);
      }
#pragma unroll
      for (int r = 0; r < 4; ++r)
        *(float2*)&REDs[((q * 8 + rq * 4 + r) * 64) + 2 * bq] = make_float2(acc[r][0], acc[r][1]);
      __syncthreads();
      if (tid < 128) {
        int b = tid & 63, u = tid >> 6;
        float g4[4];
#pragma unroll
        for (int g = 0; g < 4; ++g) {
          int slot = g * 2 + u;
          g4[g] = BIs[slot] + REDs[(0*8+slot)*64+b] + REDs[(1*8+slot)*64+b]
                            + REDs[(2*8+slot)*64+b] + REDs[(3*8+slot)*64+b];
        }
        float iv = sigm(g4[0]), fv = sigm(g4[1]), gv = tanhf(g4[2]), ov = sigm(g4[3]);
        int j = u0 + u, kk = d * 256 + j;
        float cOld = ws[CST_ + (size_t)kk * 64 + b];
        float c1 = fv * cOld + iv * gv;
        ws[CST_ + (size_t)kk * 64 + b] = c1;
        float h1 = ov * tanhf(c1);
        ws[HST_ + ((size_t)(d * 2 + nxt) * 256 + j) * 64 + b] = h1;
        if (layer == 0) ws[H1T_ + ((size_t)tt * 512 + kk) * 64 + b] = h1;
        else            ws[ENC_ + ((size_t)b * 512 + kk) * 512 + tt] = h1;
      }
      gridbar(bar);
    }
    if (layer == 0) {  // re-zero state for layer 1
      for (size_t i = gtid; i < (size_t)(2 * 2 * 256 * 64 + 512 * 64); i += (size_t)NWG * NT)
        ws[HST_ + i] = 0.f;
      // barrier happens at top of next layer iteration
    }
  }

  // ---------- decoder init: h0 = L1 final h (buf0); c0 = CST (aliased in place) ----------
  if (gtid < 32768) {
    int k = gtid >> 6, b = gtid & 63;
    int dd = k >> 8, j = k & 255;
    ws[HDT_ + (size_t)k * 64 + b] = ws[HST_ + ((size_t)(dd * 2 + 0) * 256 + j) * 64 + b];
  }
  fill_wl(WLs, BIs, Wihd, Whhd, bihd, bhhd, 1088, 512, 512, wg * 2, 1600);
  gridbar(bar);

  const float bp0 = bp[0];
  const int ab  = wg >> 2;   // attention batch owned by this WG (4 WGs / batch)

  for (int t = 0; t < 512; ++t) {
    const int cur = t & 1, nxt = cur ^ 1;

    // ===== Phase A: scores + local softmax + ctx partials (per (b, s-block of 32)) =====
    HBs[tid]       = ws[HDT_ + ((size_t)cur * 512 + tid)       * 64 + ab];
    HBs[tid + 256] = ws[HDT_ + ((size_t)cur * 512 + tid + 256) * 64 + ab];
    CBs[tid]       = ws[CST_ + (size_t)tid * 64 + ab];
    CBs[tid + 256] = ws[CST_ + (size_t)(tid + 256) * 64 + ab];
    __syncthreads();
    for (int it = 0; it < 4; ++it) {
      int sblk = (wg & 3) * 4 + it, s0 = sblk * 32;
      int kp = lane >> 5, si = lane & 31;
      float ah = 0.f, ac = 0.f;
      const float* encb = ws + ENC_ + (size_t)ab * 262144 + s0;
      int k0 = q * 128;
#pragma unroll 4
      for (int i = 0; i < 64; ++i) {
        int k = k0 + 2 * i + kp;
        float e = encb[(size_t)k * 512 + si];
        SLABs[k * 36 + si] = e;
        ah = fmaf(e, HBs[k], ah);
        ac = fmaf(e, CBs[k], ac);
      }
      ah += __shfl_xor(ah, 32);
      ac += __shfl_xor(ac, 32);
      if (kp == 0) *(float2*)&REDs[(q * 32 + si) * 2] = make_float2(ah, ac);
      __syncthreads();
      if (tid < 32) {
        float sh = REDs[(0*32+tid)*2]   + REDs[(1*32+tid)*2]   + REDs[(2*32+tid)*2]   + REDs[(3*32+tid)*2];
        float sc = REDs[(0*32+tid)*2+1] + REDs[(1*32+tid)*2+1] + REDs[(2*32+tid)*2+1] + REDs[(3*32+tid)*2+1];
        float mh = sh, mc = sc;
#pragma unroll
        for (int o = 16; o >= 1; o >>= 1) { mh = fmaxf(mh, __shfl_xor(mh, o)); mc = fmaxf(mc, __shfl_xor(mc, o)); }
        float eh = expf(sh - mh), ec = expf(sc - mc);
        float zh = eh, zc = ec;
#pragma unroll
        for (int o = 16; o >= 1; o >>= 1) { zh += __shfl_xor(zh, o); zc += __shfl_xor(zc, o); }
        WHs[tid] = eh; WCs[tid] = ec;
        if (tid == 0) {
          float* p  = ws + PMZ_ + ((size_t)0 * 64 + ab) * 32 + sblk * 2; p[0]  = mh; p[1]  = zh;
          float* p2 = ws + PMZ_ + ((size_t)1 * 64 + ab) * 32 + sblk * 2; p2[0] = mc; p2[1] = zc;
        }
      }
      __syncthreads();
#pragma unroll
      for (int kk2 = 0; kk2 < 2; ++kk2) {
        int k = tid + 256 * kk2;
        float aH = 0.f, aC = 0.f;
#pragma unroll
        for (int j = 0; j < 32; j += 4) {
          float4 e4 = *(const float4*)&SLABs[k * 36 + j];
          aH += e4.x*WHs[j] + e4.y*WHs[j+1] + e4.z*WHs[j+2] + e4.w*WHs[j+3];
          aC += e4.x*WCs[j] + e4.y*WCs[j+1] + e4.z*WCs[j+2] + e4.w*WCs[j+3];
        }
        ws[PARTH_ + ((size_t)ab * 16 + sblk) * 512 + k] = aH;
        ws[PARTC_ + ((size_t)ab * 16 + sblk) * 512 + k] = aC;
      }
      __syncthreads();
    }
    gridbar(bar);

    // ===== Phase B: flash-combine 16 s-blocks -> ctxT (one element per thread) =====
    {
      int hc = gtid >> 15, rem = gtid & 32767, b = rem >> 9, k = rem & 511;
      const float* pmz = ws + PMZ_ + ((size_t)hc * 64 + b) * 32;
      float M = -1e30f;
#pragma unroll
      for (int i = 0; i < 16; ++i) M = fmaxf(M, pmz[2 * i]);
      float Z = 0.f, val = 0.f;
      const float* part = ws + (hc ? PARTC_ : PARTH_) + ((size_t)b * 16) * 512 + k;
#pragma unroll
      for (int i = 0; i < 16; ++i) {
        float scl = expf(pmz[2 * i] - M);
        Z   += pmz[2 * i + 1] * scl;
        val += part[(size_t)i * 512] * scl;
      }
      ws[CTXT_ + ((size_t)hc * 512 + k) * 64 + b] = val / Z;
    }
    gridbar(bar);

    // ===== Phase C: decoder gate GEMM (K=1600) + pointwise + output projection =====
    {
      float acc[4][2] = {{0.f,0.f},{0.f,0.f},{0.f,0.f},{0.f,0.f}};
      const float* xb  = ws + XT_   + (size_t)t * 4096;
      const float* ctx = ws + CTXT_;
      const float* hdb = ws + HDT_  + (size_t)cur * 512 * 64;
      if      (q == 0) { dot_seg<64> (acc, xb,            WLs,             rq, bq);
                         dot_seg<336>(acc, ctx,           WLs + 64 * 8,    rq, bq); }
      else if (q == 1)   dot_seg<400>(acc, ctx + 336*64,  WLs + 400 * 8,   rq, bq);
      else if (q == 2) { dot_seg<288>(acc, ctx + 736*64,  WLs + 800 * 8,   rq, bq);
                         dot_seg<112>(acc, hdb,           WLs + 1088 * 8,  rq, bq); }
      else               dot_seg<400>(acc, hdb + 112*64,  WLs + 1200 * 8,  rq, bq);
#pragma unroll
      for (int r = 0; r < 4; ++r)
        *(float2*)&REDs[((q * 8 + rq * 4 + r) * 64) + 2 * bq] = make_float2(acc[r][0], acc[r][1]);
      __syncthreads();
      if (tid < 128) {
        int b = tid & 63, u = tid >> 6;
        float g4[4];
#pragma unroll
        for (int g = 0; g < 4; ++g) {
          int slot = g * 2 + u;
          g4[g] = BIs[slot] + REDs[(0*8+slot)*64+b] + REDs[(1*8+slot)*64+b]
                            + REDs[(2*8+slot)*64+b] + REDs[(3*8+slot)*64+b];
        }
        float iv = sigm(g4[0]), fv = sigm(g4[1]), gv = tanhf(g4[2]), ov = sigm(g4[3]);
        int k = wg * 2 + u;
        float cOld = ws[CST_ + (size_t)k * 64 + b];
        float c1 = fv * cOld + iv * gv;
        ws[CST_ + (size_t)k * 64 + b] = c1;
        float h1 = ov * tanhf(c1);
        ws[HDT_ + ((size_t)nxt * 512 + k) * 64 + b] = h1;
        float contrib = h1 * Wp[k];
        if (k == 0) contrib += bp0;
        atomicAdd(out + (size_t)b * 512 + t, contrib);
      }
      __syncthreads();
    }
    gridbar(bar);
  }
}

extern "C" void kernel_launch(void* const* d_in, const int* in_sizes, int n_in,
                              void* d_out, int out_size, void* d_ws, size_t ws_size,
                              hipStream_t stream) {
  const float* x    = (const float*)d_in[0];
  const float* Wih0 = (const float*)d_in[1];
  const float* Whh0 = (const float*)d_in[2];
  const float* bih0 = (const float*)d_in[3];
  const float* bhh0 = (const float*)d_in[4];
  const float* Wih1 = (const float*)d_in[5];
  const float* Whh1 = (const float*)d_in[6];
  const float* bih1 = (const float*)d_in[7];
  const float* bhh1 = (const float*)d_in[8];
  const float* Wihd = (const float*)d_in[9];
  const float* Whhd = (const float*)d_in[10];
  const float* bihd = (const float*)d_in[11];
  const float* bhhd = (const float*)d_in[12];
  const float* Wp   = (const float*)d_in[13];
  const float* bp   = (const float*)d_in[14];
  float* out = (float*)d_out;
  float* ws  = (float*)d_ws;

  // zero output (accumulated via atomics) and barrier counters (ws poisoned 0xAA)
  hipMemsetAsync(d_out, 0, (size_t)out_size * sizeof(float), stream);
  hipMemsetAsync(d_ws, 0, 4096, stream);

  static_assert(SMEM_F * 4 == 137504, "lds size");
  hipFuncSetAttribute((const void*)seq2seq_ker,
                      hipFuncAttributeMaxDynamicSharedMemorySize, SMEM_F * 4);

  hipLaunchKernelGGL(seq2seq_ker, dim3(NWG), dim3(NT), SMEM_F * 4, stream,
                     x, Wih0, Whh0, bih0, bhh0, Wih1, Whh1, bih1, bhh1,
                     Wihd, Whhd, bihd, bhhd, Wp, bp, out, ws);
}

// Round 2
// 108723.865 us; speedup vs baseline: 1.0200x; 1.0200x over previous
//
#include <hip/hip_runtime.h>
#include <cmath>

#define NWG 256
#define NT  512

// ---------------- workspace layout (float offsets) ----------------
static constexpr size_t BAR_  = 0;                               // barrier area (8192 floats = 32KB)
static constexpr size_t XT_   = 8192;                            // xT[t][k][b]      512*64*64
static constexpr size_t H1T_  = XT_   + (size_t)512*64*64;       // H1T[t][k][b]     512*512*64
static constexpr size_t ENC_  = H1T_  + (size_t)512*512*64;      // ENC[b][k][s]     64*512*512
static constexpr size_t HST_  = ENC_  + (size_t)64*512*512;      // HST[d][buf][j][b] 2*2*256*64
static constexpr size_t CST_  = HST_  + (size_t)2*2*256*64;      // CST[k][b]        512*64
static constexpr size_t HDT_  = CST_  + (size_t)512*64;          // hdT[buf][k][b]   2*512*64
static constexpr size_t CTXT_ = HDT_  + (size_t)2*512*64;        // ctxT[k][b]       1024*64
static constexpr size_t PARTH_= CTXT_ + (size_t)1024*64;         // partH[b][sblk][k] 64*16*512
static constexpr size_t PARTC_= PARTH_+ (size_t)64*16*512;
static constexpr size_t PMZ_  = PARTC_+ (size_t)64*16*512;       // [hc][b][sblk][2]  2*64*16*2

// ---------------- LDS layout (float offsets) ----------------
static constexpr int WL_O   = 0;              // weights [k][8 slots]   12800 (dec K=1600)
static constexpr int SLAB_O = 12800;          // enc slab [512][36]     18432
static constexpr int RED_O  = SLAB_O + 18432; // partials [8][8][64]     4096
static constexpr int HB_O   = RED_O  + 4096;  // dec h_b[512]
static constexpr int CB_O   = HB_O   + 512;   // dec c_b[512]
static constexpr int WH_O   = CB_O   + 512;   // softmax wts h [32]
static constexpr int WC_O   = WH_O   + 32;    // softmax wts c [32]
static constexpr int BI_O   = WC_O   + 32;    // bias [8]
static constexpr int SMEM_F = BI_O   + 8;     // 36424 floats = 145696 B

#define AT_LD(p,o)  __hip_atomic_load((p), (o), __HIP_MEMORY_SCOPE_AGENT)
#define AT_ST(p,v,o) __hip_atomic_store((p), (v), (o), __HIP_MEMORY_SCOPE_AGENT)
#define AT_ADD(p,v,o) __hip_atomic_fetch_add((p), (v), (o), __HIP_MEMORY_SCOPE_AGENT)

__device__ __forceinline__ float sigm(float v) { return 1.f / (1.f + expf(-v)); }

// 3-level tree barrier, fan-out 8. Layout (uints, stride 32 = one 128B line):
// [0]=gen  [32]=root  [64 + m*32] m<4 = mids  [192 + l*32] l<32 = leaves
__device__ __forceinline__ void treebar(unsigned* base, int wgl, unsigned nroot) {
  __syncthreads();
  if (threadIdx.x == 0) {
    __threadfence();
    unsigned* gen = base;
    unsigned g = AT_LD(gen, __ATOMIC_RELAXED);
    unsigned* leaf = base + 192 + (wgl >> 3) * 32;
    if (AT_ADD(leaf, 1u, __ATOMIC_ACQ_REL) == 7u) {
      AT_ST(leaf, 0u, __ATOMIC_RELAXED);
      unsigned* mid = base + 64 + (wgl >> 6) * 32;
      if (AT_ADD(mid, 1u, __ATOMIC_ACQ_REL) == 7u) {
        AT_ST(mid, 0u, __ATOMIC_RELAXED);
        unsigned* root = base + 32;
        if (AT_ADD(root, 1u, __ATOMIC_ACQ_REL) == nroot - 1u) {
          AT_ST(root, 0u, __ATOMIC_RELAXED);
          AT_ADD(gen, 1u, __ATOMIC_RELEASE);
        }
      }
    }
    while (AT_LD(gen, __ATOMIC_ACQUIRE) == g) __builtin_amdgcn_s_sleep(2);
  }
  __syncthreads();
}

// tiny n-WG barrier: [0]=gen [32]=count
__device__ __forceinline__ void minibar(unsigned* base, unsigned n) {
  __syncthreads();
  if (threadIdx.x == 0) {
    __threadfence();
    unsigned g = AT_LD(base, __ATOMIC_RELAXED);
    if (AT_ADD(base + 32, 1u, __ATOMIC_ACQ_REL) == n - 1u) {
      AT_ST(base + 32, 0u, __ATOMIC_RELAXED);
      AT_ADD(base, 1u, __ATOMIC_RELEASE);
    }
    while (AT_LD(base, __ATOMIC_ACQUIRE) == g) __builtin_amdgcn_s_sleep(2);
  }
  __syncthreads();
}

// One K-segment of the gate GEMM. Lane tile: 4 rows (slots rq*4..rq*4+3) x 2 batches.
template<int N>
__device__ __forceinline__ void dot_seg(float (&acc)[4][2], const float* kb,
                                        const float* wl, int rq, int bq) {
#pragma unroll 16
  for (int i = 0; i < N; ++i) {
    float2 hv = *(const float2*)(kb + (size_t)i * 64 + 2 * bq);
    float4 wv = *(const float4*)(wl + i * 8 + rq * 4);
    acc[0][0] = fmaf(wv.x, hv.x, acc[0][0]); acc[0][1] = fmaf(wv.x, hv.y, acc[0][1]);
    acc[1][0] = fmaf(wv.y, hv.x, acc[1][0]); acc[1][1] = fmaf(wv.y, hv.y, acc[1][1]);
    acc[2][0] = fmaf(wv.z, hv.x, acc[2][0]); acc[2][1] = fmaf(wv.z, hv.y, acc[2][1]);
    acc[3][0] = fmaf(wv.w, hv.x, acc[3][0]); acc[3][1] = fmaf(wv.w, hv.y, acc[3][1]);
  }
}

// Load this WG's 8 gate rows (2 units x 4 gates, slot = g*2+u) into LDS, plus bias.
__device__ void fill_wl(float* WLs, float* BIs,
                        const float* Wih, const float* Whh,
                        const float* bih, const float* bhh,
                        int KI, int KH, int gstride, int u0, int K) {
  for (int idx = threadIdx.x; idx < K * 8; idx += NT) {
    int k = idx >> 3, slot = idx & 7;
    int row = (slot >> 1) * gstride + u0 + (slot & 1);
    WLs[k * 8 + slot] = (k < KI) ? Wih[(size_t)row * KI + k]
                                 : Whh[(size_t)row * KH + (k - KI)];
  }
  if (threadIdx.x < 8) {
    int row = ((int)threadIdx.x >> 1) * gstride + u0 + ((int)threadIdx.x & 1);
    BIs[threadIdx.x] = bih[row] + bhh[row];
  }
  __syncthreads();
}

extern "C" __global__ void __launch_bounds__(NT, 2)
seq2seq_ker(const float* __restrict__ x,
            const float* __restrict__ Wih0, const float* __restrict__ Whh0,
            const float* __restrict__ bih0, const float* __restrict__ bhh0,
            const float* __restrict__ Wih1, const float* __restrict__ Whh1,
            const float* __restrict__ bih1, const float* __restrict__ bhh1,
            const float* __restrict__ Wihd, const float* __restrict__ Whhd,
            const float* __restrict__ bihd, const float* __restrict__ bhhd,
            const float* __restrict__ Wp,   const float* __restrict__ bp,
            float* out, float* ws) {
  extern __shared__ float smem[];
  float* WLs   = smem + WL_O;
  float* SLABs = smem + SLAB_O;
  float* REDs  = smem + RED_O;
  float* HBs   = smem + HB_O;
  float* CBs   = smem + CB_O;
  float* WHs   = smem + WH_O;
  float* WCs   = smem + WC_O;
  float* BIs   = smem + BI_O;

  unsigned* bar = (unsigned*)ws;          // tree k at bar + k*1280; minis at bar+3840+ab*64
  const int tid  = threadIdx.x;
  const int wg   = blockIdx.x;
  const int gtid = wg * NT + tid;
  const int lane = tid & 63, q = tid >> 6;        // q in 0..7
  const int rq = lane & 1, bq = lane >> 1;

  // ---------- prep: transpose x -> xT[t][k][b]; zero h/c state ----------
  for (size_t i = gtid; i < (size_t)512 * 64 * 64; i += (size_t)NWG * NT) {
    int b = (int)(i & 63), k = (int)((i >> 6) & 63), t = (int)(i >> 12);
    ws[XT_ + i] = x[((size_t)b * 512 + t) * 64 + k];
  }
  for (size_t i = gtid; i < (size_t)(2 * 2 * 256 * 64 + 512 * 64); i += (size_t)NWG * NT)
    ws[HST_ + i] = 0.f;   // HST + CST are adjacent

  // ---------- encoder: 2 layers ----------
  const int d  = wg >> 7;            // direction
  const int u0 = (wg & 127) * 2;     // this WG's 2 hidden units
  unsigned* dirbar = bar + (1 + d) * 1280;
  const int wgl = wg & 127;

  for (int layer = 0; layer < 2; ++layer) {
    if (layer == 0)
      fill_wl(WLs, BIs, Wih0 + (size_t)d * 1024 * 64,  Whh0 + (size_t)d * 1024 * 256,
              bih0 + d * 1024, bhh0 + d * 1024, 64, 256, 256, u0, 320);
    else
      fill_wl(WLs, BIs, Wih1 + (size_t)d * 1024 * 512, Whh1 + (size_t)d * 1024 * 256,
              bih1 + d * 1024, bhh1 + d * 1024, 512, 256, 256, u0, 768);
    treebar(bar, wg, 4);   // full grid: state zeroed + weights ready, both dirs done prev layer

    for (int t = 0; t < 512; ++t) {
      const int cur = t & 1, nxt = cur ^ 1;
      const int tt = d ? (511 - t) : t;
      float acc[4][2] = {{0.f,0.f},{0.f,0.f},{0.f,0.f},{0.f,0.f}};
      const float* hbase = ws + HST_ + ((size_t)(d * 2 + cur) * 256) * 64;
      if (layer == 0) {
        const float* xb = ws + XT_ + (size_t)tt * 4096;
        switch (q) {
          case 0: dot_seg<40>(acc, xb,            WLs,           rq, bq); break;
          case 1: dot_seg<24>(acc, xb + 40*64,    WLs + 40*8,    rq, bq);
                  dot_seg<16>(acc, hbase,         WLs + 64*8,    rq, bq); break;
          case 2: dot_seg<40>(acc, hbase + 16*64, WLs + 80*8,    rq, bq); break;
          case 3: dot_seg<40>(acc, hbase + 56*64, WLs + 120*8,   rq, bq); break;
          case 4: dot_seg<40>(acc, hbase + 96*64, WLs + 160*8,   rq, bq); break;
          case 5: dot_seg<40>(acc, hbase + 136*64,WLs + 200*8,   rq, bq); break;
          case 6: dot_seg<40>(acc, hbase + 176*64,WLs + 240*8,   rq, bq); break;
          default:dot_seg<40>(acc, hbase + 216*64,WLs + 280*8,   rq, bq); break;
        }
      } else {
        const float* ib = ws + H1T_ + (size_t)tt * 512 * 64;
        switch (q) {
          case 0: dot_seg<96>(acc, ib,            WLs,           rq, bq); break;
          case 1: dot_seg<96>(acc, ib + 96*64,    WLs + 96*8,    rq, bq); break;
          case 2: dot_seg<96>(acc, ib + 192*64,   WLs + 192*8,   rq, bq); break;
          case 3: dot_seg<96>(acc, ib + 288*64,   WLs + 288*8,   rq, bq); break;
          case 4: dot_seg<96>(acc, ib + 384*64,   WLs + 384*8,   rq, bq); break;
          case 5: dot_seg<32>(acc, ib + 480*64,   WLs + 480*8,   rq, bq);
                  dot_seg<64>(acc, hbase,         WLs + 512*8,   rq, bq); break;
          case 6: dot_seg<96>(acc, hbase + 64*64, WLs + 576*8,   rq, bq); break;
          default:dot_seg<96>(acc, hbase + 160*64,WLs + 672*8,   rq, bq); break;
        }
      }
#pragma unroll
      for (int r = 0; r < 4; ++r)
        *(float2*)&REDs[((q * 8 + rq * 4 + r) * 64) + 2 * bq] = make_float2(acc[r][0], acc[r][1]);
      __syncthreads();
      if (tid < 128) {
        int b = tid & 63, u = tid >> 6;
        float g4[4];
#pragma unroll
        for (int g = 0; g < 4; ++g) {
          int slot = g * 2 + u;
          float s = BIs[slot];
#pragma unroll
          for (int qq = 0; qq < 8; ++qq) s += REDs[(qq * 8 + slot) * 64 + b];
          g4[g] = s;
        }
        float iv = sigm(g4[0]), fv = sigm(g4[1]), gv = tanhf(g4[2]), ov = sigm(g4[3]);
        int j = u0 + u, kk = d * 256 + j;
        float cOld = ws[CST_ + (size_t)kk * 64 + b];
        float c1 = fv * cOld + iv * gv;
        ws[CST_ + (size_t)kk * 64 + b] = c1;
        float h1 = ov * tanhf(c1);
        ws[HST_ + ((size_t)(d * 2 + nxt) * 256 + j) * 64 + b] = h1;
        if (layer == 0) ws[H1T_ + ((size_t)tt * 512 + kk) * 64 + b] = h1;
        else            ws[ENC_ + ((size_t)b * 512 + kk) * 512 + tt] = h1;
      }
      treebar(dirbar, wgl, 2);   // direction-local
    }
    treebar(bar, wg, 4);         // both directions done with this layer
    if (layer == 0) {  // re-zero state for layer 1 (fenced by treebar at top of next iter)
      for (size_t i = gtid; i < (size_t)(2 * 2 * 256 * 64 + 512 * 64); i += (size_t)NWG * NT)
        ws[HST_ + i] = 0.f;
    }
  }

  // ---------- decoder init: h0 = L1 final h (buf0); c0 = CST (aliased in place) ----------
  if (gtid < 32768) {
    int k = gtid >> 6, b = gtid & 63;
    int dd = k >> 8, j = k & 255;
    ws[HDT_ + (size_t)k * 64 + b] = ws[HST_ + ((size_t)(dd * 2 + 0) * 256 + j) * 64 + b];
  }
  fill_wl(WLs, BIs, Wihd, Whhd, bihd, bhhd, 1088, 512, 512, wg * 2, 1600);
  treebar(bar, wg, 4);

  const float bp0 = bp[0];
  const int ab = wg >> 2;          // attention batch owned by this WG (4 WGs / batch)
  unsigned* mbar = bar + 3840 + ab * 64;
  const int kp = lane >> 3, sv = lane & 7;

  for (int t = 0; t < 512; ++t) {
    const int cur = t & 1, nxt = cur ^ 1;

    // ===== Phase A: scores + local softmax + ctx partials (per (b, s-block of 32)) =====
    HBs[tid] = ws[HDT_ + ((size_t)cur * 512 + tid) * 64 + ab];
    CBs[tid] = ws[CST_ + (size_t)tid * 64 + ab];
    __syncthreads();
    for (int it = 0; it < 4; ++it) {
      int sblk = (wg & 3) * 4 + it, s0 = sblk * 32;
      const float* encb = ws + ENC_ + (size_t)ab * 262144 + s0;
      float ah[4] = {0.f,0.f,0.f,0.f}, ac[4] = {0.f,0.f,0.f,0.f};
#pragma unroll
      for (int i = 0; i < 8; ++i) {
        int k = q * 64 + i * 8 + kp;
        float4 e4 = *(const float4*)(encb + (size_t)k * 512 + sv * 4);
        *(float4*)&SLABs[k * 36 + sv * 4] = e4;
        float hk = HBs[k], ck = CBs[k];
        ah[0] = fmaf(e4.x, hk, ah[0]); ah[1] = fmaf(e4.y, hk, ah[1]);
        ah[2] = fmaf(e4.z, hk, ah[2]); ah[3] = fmaf(e4.w, hk, ah[3]);
        ac[0] = fmaf(e4.x, ck, ac[0]); ac[1] = fmaf(e4.y, ck, ac[1]);
        ac[2] = fmaf(e4.z, ck, ac[2]); ac[3] = fmaf(e4.w, ck, ac[3]);
      }
#pragma unroll
      for (int m = 8; m <= 32; m <<= 1)
#pragma unroll
        for (int j2 = 0; j2 < 4; ++j2) {
          ah[j2] += __shfl_xor(ah[j2], m);
          ac[j2] += __shfl_xor(ac[j2], m);
        }
      if (lane < 8) {   // kp==0 lanes, lane == sv
        *(float4*)&REDs[q * 32 + lane * 4]       = make_float4(ah[0], ah[1], ah[2], ah[3]);
        *(float4*)&REDs[256 + q * 32 + lane * 4] = make_float4(ac[0], ac[1], ac[2], ac[3]);
      }
      __syncthreads();
      if (tid < 32) {
        float sh = 0.f, sc = 0.f;
#pragma unroll
        for (int qq = 0; qq < 8; ++qq) { sh += REDs[qq * 32 + tid]; sc += REDs[256 + qq * 32 + tid]; }
        float mh = sh, mc = sc;
#pragma unroll
        for (int o = 16; o >= 1; o >>= 1) { mh = fmaxf(mh, __shfl_xor(mh, o)); mc = fmaxf(mc, __shfl_xor(mc, o)); }
        float eh = expf(sh - mh), ec = expf(sc - mc);
        float zh = eh, zc = ec;
#pragma unroll
        for (int o = 16; o >= 1; o >>= 1) { zh += __shfl_xor(zh, o); zc += __shfl_xor(zc, o); }
        WHs[tid] = eh; WCs[tid] = ec;
        if (tid == 0) {
          float* p  = ws + PMZ_ + ((size_t)0 * 64 + ab) * 32 + sblk * 2; p[0]  = mh; p[1]  = zh;
          float* p2 = ws + PMZ_ + ((size_t)1 * 64 + ab) * 32 + sblk * 2; p2[0] = mc; p2[1] = zc;
        }
      }
      __syncthreads();
      {
        int k = tid;   // 512 threads cover k=0..511
        float aH = 0.f, aC = 0.f;
#pragma unroll
        for (int j = 0; j < 32; j += 4) {
          float4 e4 = *(const float4*)&SLABs[k * 36 + j];
          aH += e4.x*WHs[j] + e4.y*WHs[j+1] + e4.z*WHs[j+2] + e4.w*WHs[j+3];
          aC += e4.x*WCs[j] + e4.y*WCs[j+1] + e4.z*WCs[j+2] + e4.w*WCs[j+3];
        }
        ws[PARTH_ + ((size_t)ab * 16 + sblk) * 512 + k] = aH;
        ws[PARTC_ + ((size_t)ab * 16 + sblk) * 512 + k] = aC;
      }
      __syncthreads();
    }
    minibar(mbar, 4);   // only this batch's 4 WGs need each other's partials

    // ===== Phase B: flash-combine 16 s-blocks -> ctxT (batch-local assignment) =====
    {
      int lid = (wg & 3) * NT + tid;
      if (lid < 1024) {
        int hc = lid >> 9, k = lid & 511, b = ab;
        const float* pmz = ws + PMZ_ + ((size_t)hc * 64 + b) * 32;
        float M = -1e30f;
#pragma unroll
        for (int i = 0; i < 16; ++i) M = fmaxf(M, pmz[2 * i]);
        float Z = 0.f, val = 0.f;
        const float* part = ws + (hc ? PARTC_ : PARTH_) + ((size_t)b * 16) * 512 + k;
#pragma unroll
        for (int i = 0; i < 16; ++i) {
          float scl = expf(pmz[2 * i] - M);
          Z   += pmz[2 * i + 1] * scl;
          val += part[(size_t)i * 512] * scl;
        }
        ws[CTXT_ + ((size_t)hc * 512 + k) * 64 + b] = val / Z;
      }
    }
    treebar(bar, wg, 4);

    // ===== Phase C: decoder gate GEMM (K=1600) + pointwise + output projection =====
    {
      float acc[4][2] = {{0.f,0.f},{0.f,0.f},{0.f,0.f},{0.f,0.f}};
      const float* xb  = ws + XT_   + (size_t)t * 4096;
      const float* ctx = ws + CTXT_;
      const float* hdb = ws + HDT_  + (size_t)cur * 512 * 64;
      switch (q) {
        case 0: dot_seg<64> (acc, xb,            WLs,            rq, bq);
                dot_seg<136>(acc, ctx,           WLs + 64*8,     rq, bq); break;
        case 1: dot_seg<200>(acc, ctx + 136*64,  WLs + 200*8,    rq, bq); break;
        case 2: dot_seg<200>(acc, ctx + 336*64,  WLs + 400*8,    rq, bq); break;
        case 3: dot_seg<200>(acc, ctx + 536*64,  WLs + 600*8,    rq, bq); break;
        case 4: dot_seg<200>(acc, ctx + 736*64,  WLs + 800*8,    rq, bq); break;
        case 5: dot_seg<88> (acc, ctx + 936*64,  WLs + 1000*8,   rq, bq);
                dot_seg<112>(acc, hdb,           WLs + 1088*8,   rq, bq); break;
        case 6: dot_seg<200>(acc, hdb + 112*64,  WLs + 1200*8,   rq, bq); break;
        default:dot_seg<200>(acc, hdb + 312*64,  WLs + 1400*8,   rq, bq); break;
      }
#pragma unroll
      for (int r = 0; r < 4; ++r)
        *(float2*)&REDs[((q * 8 + rq * 4 + r) * 64) + 2 * bq] = make_float2(acc[r][0], acc[r][1]);
      __syncthreads();
      if (tid < 128) {
        int b = tid & 63, u = tid >> 6;
        float g4[4];
#pragma unroll
        for (int g = 0; g < 4; ++g) {
          int slot = g * 2 + u;
          float s = BIs[slot];
#pragma unroll
          for (int qq = 0; qq < 8; ++qq) s += REDs[(qq * 8 + slot) * 64 + b];
          g4[g] = s;
        }
        float iv = sigm(g4[0]), fv = sigm(g4[1]), gv = tanhf(g4[2]), ov = sigm(g4[3]);
        int k = wg * 2 + u;
        float cOld = ws[CST_ + (size_t)k * 64 + b];
        float c1 = fv * cOld + iv * gv;
        ws[CST_ + (size_t)k * 64 + b] = c1;
        float h1 = ov * tanhf(c1);
        ws[HDT_ + ((size_t)nxt * 512 + k) * 64 + b] = h1;
        float contrib = h1 * Wp[k];
        if (k == 0) contrib += bp0;
        atomicAdd(out + (size_t)b * 512 + t, contrib);
      }
    }
    treebar(bar, wg, 4);
  }
}

extern "C" void kernel_launch(void* const* d_in, const int* in_sizes, int n_in,
                              void* d_out, int out_size, void* d_ws, size_t ws_size,
                              hipStream_t stream) {
  const float* x    = (const float*)d_in[0];
  const float* Wih0 = (const float*)d_in[1];
  const float* Whh0 = (const float*)d_in[2];
  const float* bih0 = (const float*)d_in[3];
  const float* bhh0 = (const float*)d_in[4];
  const float* Wih1 = (const float*)d_in[5];
  const float* Whh1 = (const float*)d_in[6];
  const float* bih1 = (const float*)d_in[7];
  const float* bhh1 = (const float*)d_in[8];
  const float* Wihd = (const float*)d_in[9];
  const float* Whhd = (const float*)d_in[10];
  const float* bihd = (const float*)d_in[11];
  const float* bhhd = (const float*)d_in[12];
  const float* Wp   = (const float*)d_in[13];
  const float* bp   = (const float*)d_in[14];
  float* out = (float*)d_out;
  float* ws  = (float*)d_ws;

  // zero output (accumulated via atomics) and barrier counters (ws poisoned 0xAA)
  hipMemsetAsync(d_out, 0, (size_t)out_size * sizeof(float), stream);
  hipMemsetAsync(d_ws, 0, 32768, stream);

  static_assert(SMEM_F * 4 == 145696, "lds size");
  hipFuncSetAttribute((const void*)seq2seq_ker,
                      hipFuncAttributeMaxDynamicSharedMemorySize, SMEM_F * 4);

  hipLaunchKernelGGL(seq2seq_ker, dim3(NWG), dim3(NT), SMEM_F * 4, stream,
                     x, Wih0, Whh0, bih0, bhh0, Wih1, Whh1, bih1, bhh1,
                     Wihd, Whhd, bihd, bhhd, Wp, bp, out, ws);
}

// Round 3
// 62142.114 us; speedup vs baseline: 1.7846x; 1.7496x over previous
//
#include <hip/hip_runtime.h>
#include <cmath>

#define NWG 256
#define NT  512

// ---------------- workspace layout (float offsets) ----------------
static constexpr size_t XT_   = 8192;                        // xT[t][k][b] 512*64*64
static constexpr size_t H1T_  = XT_   + (size_t)512*64*64;   // H1T[t][k][b] 512*512*64
static constexpr size_t ENC_  = H1T_  + (size_t)512*512*64;  // ENC[b][k][s] 64*512*512
static constexpr size_t HST_  = ENC_  + (size_t)64*512*512;  // enc h [d][buf][j][b] 2*2*256*64 (atomic)
static constexpr size_t HDT_  = HST_  + (size_t)2*2*256*64;  // dec h [buf][k][b] 2*512*64 (atomic)
static constexpr size_t CSTD_ = HDT_  + (size_t)2*512*64;    // dec c [k][b] 512*64 (atomic)
static constexpr size_t CTXD_ = CSTD_ + (size_t)512*64;      // ctx [hc*512+k][b] 1024*64 (atomic)
static constexpr size_t SCO_  = CTXD_ + (size_t)1024*64;     // scores [b][hc][s] 64*2*512 (atomic)

// ---------------- LDS layout (float offsets) ----------------
static constexpr int WL_O  = 0;              // weights [k][8 slots] (dec K=1600) 12800
static constexpr int RED_O = 12800;          // reduce scratch 4096
static constexpr int HB_O  = RED_O + 4096;   // h[512]
static constexpr int CB_O  = HB_O + 512;     // c[512]
static constexpr int WH_O  = CB_O + 512;     // softmax wts h [512]
static constexpr int WC_O  = WH_O + 512;     // softmax wts c [512]
static constexpr int PRJ_O = WC_O + 512;     // projection partials [8]
static constexpr int BI_O  = PRJ_O + 8;      // bias [8]
static constexpr int SMEM_F = BI_O + 8;      // 18960 floats = 75840 B

__device__ __forceinline__ float sigm(float v) { return 1.f / (1.f + expf(-v)); }

__device__ __forceinline__ unsigned uld(unsigned* p) {
  return __hip_atomic_load(p, __ATOMIC_RELAXED, __HIP_MEMORY_SCOPE_AGENT);
}
__device__ __forceinline__ unsigned uadd(unsigned* p) {
  return __hip_atomic_fetch_add(p, 1u, __ATOMIC_RELAXED, __HIP_MEMORY_SCOPE_AGENT);
}
__device__ __forceinline__ float ald(const float* p) {
  return __hip_atomic_load(p, __ATOMIC_RELAXED, __HIP_MEMORY_SCOPE_AGENT);
}
__device__ __forceinline__ void ast(float* p, float v) {
  __hip_atomic_store(p, v, __ATOMIC_RELAXED, __HIP_MEMORY_SCOPE_AGENT);
}

// Global 256-WG relaxed barrier: monotonic 3-level tree (32 leaves x8, 4 mids x8, root x4).
// bar layout (uints): gen@0, leaf l @32+l*32, mid m @1056+m*32, root @1184.
__device__ __forceinline__ void gbar(unsigned* bar, int wg) {
  __syncthreads();   // compiler drains vmcnt before s_barrier -> prior stores complete
  if (threadIdx.x == 0) {
    unsigned g = uld(bar);
    if (((uadd(&bar[32 + (wg >> 3) * 32]) + 1) & 7) == 0)
      if (((uadd(&bar[1056 + (wg >> 6) * 32]) + 1) & 7) == 0)
        if (((uadd(&bar[1184]) + 1) & 3) == 0)
          uadd(bar);
    while (uld(bar) == g) __builtin_amdgcn_s_sleep(1);
  }
  __syncthreads();
}

// Same but with real fences (phase boundaries only): release+acquire for bulk normal stores.
__device__ __forceinline__ void fullbar(unsigned* bar, int wg) {
  __syncthreads();
  if (threadIdx.x == 0) {
    __threadfence();   // release: L2 writeback
    unsigned g = uld(bar);
    if (((uadd(&bar[32 + (wg >> 3) * 32]) + 1) & 7) == 0)
      if (((uadd(&bar[1056 + (wg >> 6) * 32]) + 1) & 7) == 0)
        if (((uadd(&bar[1184]) + 1) & 3) == 0)
          uadd(bar);
    while (uld(bar) == g) __builtin_amdgcn_s_sleep(8);
    __threadfence();   // acquire: invalidate
  }
  __syncthreads();
}

// Direction-local 128-WG relaxed barrier: 2-level (16 leaves x8, root x16).
// base: gen@0, leaf l @32+l*32, root @544.
__device__ __forceinline__ void dbar(unsigned* base, int wgl) {
  __syncthreads();
  if (threadIdx.x == 0) {
    unsigned g = uld(base);
    if (((uadd(&base[32 + (wgl >> 3) * 32]) + 1) & 7) == 0)
      if (((uadd(&base[544]) + 1) & 15) == 0)
        uadd(base);
    while (uld(base) == g) __builtin_amdgcn_s_sleep(1);
  }
  __syncthreads();
}

// 4-WG relaxed minibar: gen@0, cnt@32.
__device__ __forceinline__ void mbar4(unsigned* base) {
  __syncthreads();
  if (threadIdx.x == 0) {
    unsigned g = uld(base);
    if (((uadd(&base[32]) + 1) & 3) == 0) uadd(base);
    while (uld(base) == g) __builtin_amdgcn_s_sleep(1);
  }
  __syncthreads();
}

// Gate-GEMM K-segment, normal (cached) activation loads. Lane: 4 rows x 2 batches.
template<int N>
__device__ __forceinline__ void dot_seg(float (&acc)[4][2], const float* kb,
                                        const float* wl, int rq, int bq) {
#pragma unroll 8
  for (int i = 0; i < N; ++i) {
    float2 hv = *(const float2*)(kb + (size_t)i * 64 + 2 * bq);
    float4 wv = *(const float4*)(wl + i * 8 + rq * 4);
    acc[0][0] = fmaf(wv.x, hv.x, acc[0][0]); acc[0][1] = fmaf(wv.x, hv.y, acc[0][1]);
    acc[1][0] = fmaf(wv.y, hv.x, acc[1][0]); acc[1][1] = fmaf(wv.y, hv.y, acc[1][1]);
    acc[2][0] = fmaf(wv.z, hv.x, acc[2][0]); acc[2][1] = fmaf(wv.z, hv.y, acc[2][1]);
    acc[3][0] = fmaf(wv.w, hv.x, acc[3][0]); acc[3][1] = fmaf(wv.w, hv.y, acc[3][1]);
  }
}

// Same, but activations via relaxed agent atomic loads (LLC-coherent state).
template<int N>
__device__ __forceinline__ void dot_seg_at(float (&acc)[4][2], const float* kb,
                                           const float* wl, int rq, int bq) {
#pragma unroll 8
  for (int i = 0; i < N; ++i) {
    const float* p = kb + (size_t)i * 64 + 2 * bq;
    float h0 = ald(p), h1 = ald(p + 1);
    float4 wv = *(const float4*)(wl + i * 8 + rq * 4);
    acc[0][0] = fmaf(wv.x, h0, acc[0][0]); acc[0][1] = fmaf(wv.x, h1, acc[0][1]);
    acc[1][0] = fmaf(wv.y, h0, acc[1][0]); acc[1][1] = fmaf(wv.y, h1, acc[1][1]);
    acc[2][0] = fmaf(wv.z, h0, acc[2][0]); acc[2][1] = fmaf(wv.z, h1, acc[2][1]);
    acc[3][0] = fmaf(wv.w, h0, acc[3][0]); acc[3][1] = fmaf(wv.w, h1, acc[3][1]);
  }
}

// Load this WG's 8 gate rows (2 units x 4 gates, slot = g*2+u) into LDS, plus bias.
__device__ void fill_wl(float* WLs, float* BIs,
                        const float* Wih, const float* Whh,
                        const float* bih, const float* bhh,
                        int KI, int KH, int gstride, int u0, int K) {
  for (int idx = threadIdx.x; idx < K * 8; idx += NT) {
    int k = idx >> 3, slot = idx & 7;
    int row = (slot >> 1) * gstride + u0 + (slot & 1);
    WLs[k * 8 + slot] = (k < KI) ? Wih[(size_t)row * KI + k]
                                 : Whh[(size_t)row * KH + (k - KI)];
  }
  if (threadIdx.x < 8) {
    int row = ((int)threadIdx.x >> 1) * gstride + u0 + ((int)threadIdx.x & 1);
    BIs[threadIdx.x] = bih[row] + bhh[row];
  }
  __syncthreads();
}

extern "C" __global__ void __launch_bounds__(NT, 1)
seq2seq_ker(const float* __restrict__ x,
            const float* __restrict__ Wih0, const float* __restrict__ Whh0,
            const float* __restrict__ bih0, const float* __restrict__ bhh0,
            const float* __restrict__ Wih1, const float* __restrict__ Whh1,
            const float* __restrict__ bih1, const float* __restrict__ bhh1,
            const float* __restrict__ Wihd, const float* __restrict__ Whhd,
            const float* __restrict__ bihd, const float* __restrict__ bhhd,
            const float* __restrict__ Wp,   const float* __restrict__ bp,
            float* out, float* ws) {
  extern __shared__ float smem[];
  float* WLs = smem + WL_O;
  float* REDs = smem + RED_O;
  float* HBs = smem + HB_O;
  float* CBs = smem + CB_O;
  float* WHs = smem + WH_O;
  float* WCs = smem + WC_O;
  float* PRJ = smem + PRJ_O;
  float* BIs = smem + BI_O;

  unsigned* bar = (unsigned*)ws;               // global tree @0
  const int tid = threadIdx.x;
  const int wg  = blockIdx.x;
  const int gtid = wg * NT + tid;
  const int lane = tid & 63, q = tid >> 6, w = q;
  const int rq = lane & 1, bq = lane >> 1;

  // ---------- prep: transpose x -> xT[t][k][b]; zero encoder h state ----------
  for (size_t i = gtid; i < (size_t)512 * 64 * 64; i += (size_t)NWG * NT) {
    int b = (int)(i & 63), k = (int)((i >> 6) & 63), t = (int)(i >> 12);
    ws[XT_ + i] = x[((size_t)b * 512 + t) * 64 + k];
  }
  if (gtid < 65536) ast(ws + HST_ + gtid, 0.f);

  // ---------- encoder: 2 layers ----------
  const int d  = wg >> 7;                 // direction
  const int u0 = (wg & 127) * 2;          // this WG's 2 hidden units within dir
  const int wgl = wg & 127;
  unsigned* dirbar = bar + 2048 + d * 1024;

  float cReg = 0.f, hReg = 0.f;

  for (int layer = 0; layer < 2; ++layer) {
    if (layer == 0)
      fill_wl(WLs, BIs, Wih0 + (size_t)d * 1024 * 64,  Whh0 + (size_t)d * 1024 * 256,
              bih0 + d * 1024, bhh0 + d * 1024, 64, 256, 256, u0, 320);
    else
      fill_wl(WLs, BIs, Wih1 + (size_t)d * 1024 * 512, Whh1 + (size_t)d * 1024 * 256,
              bih1 + d * 1024, bhh1 + d * 1024, 512, 256, 256, u0, 768);
    fullbar(bar, wg);   // XT / H1T bulk data + zeroed state visible

    for (int t = 0; t < 512; ++t) {
      const int cur = t & 1, nxt = cur ^ 1;
      const int tt = d ? (511 - t) : t;
      float acc[4][2] = {{0.f,0.f},{0.f,0.f},{0.f,0.f},{0.f,0.f}};
      const float* hbase = ws + HST_ + ((size_t)(d * 2 + cur) * 256) * 64;
      if (layer == 0) {
        const float* xb = ws + XT_ + (size_t)tt * 4096;
        switch (q) {
          case 0: dot_seg<40>(acc, xb, WLs, rq, bq); break;
          case 1: dot_seg<24>(acc, xb + 40*64, WLs + 40*8, rq, bq);
                  dot_seg_at<16>(acc, hbase, WLs + 64*8, rq, bq); break;
          case 2: dot_seg_at<40>(acc, hbase + 16*64,  WLs + 80*8,  rq, bq); break;
          case 3: dot_seg_at<40>(acc, hbase + 56*64,  WLs + 120*8, rq, bq); break;
          case 4: dot_seg_at<40>(acc, hbase + 96*64,  WLs + 160*8, rq, bq); break;
          case 5: dot_seg_at<40>(acc, hbase + 136*64, WLs + 200*8, rq, bq); break;
          case 6: dot_seg_at<40>(acc, hbase + 176*64, WLs + 240*8, rq, bq); break;
          default:dot_seg_at<40>(acc, hbase + 216*64, WLs + 280*8, rq, bq); break;
        }
      } else {
        const float* ib = ws + H1T_ + (size_t)tt * 512 * 64;
        switch (q) {
          case 0: dot_seg<96>(acc, ib,          WLs,         rq, bq); break;
          case 1: dot_seg<96>(acc, ib + 96*64,  WLs + 96*8,  rq, bq); break;
          case 2: dot_seg<96>(acc, ib + 192*64, WLs + 192*8, rq, bq); break;
          case 3: dot_seg<96>(acc, ib + 288*64, WLs + 288*8, rq, bq); break;
          case 4: dot_seg<96>(acc, ib + 384*64, WLs + 384*8, rq, bq); break;
          case 5: dot_seg<32>(acc, ib + 480*64, WLs + 480*8, rq, bq);
                  dot_seg_at<64>(acc, hbase, WLs + 512*8, rq, bq); break;
          case 6: dot_seg_at<96>(acc, hbase + 64*64,  WLs + 576*8, rq, bq); break;
          default:dot_seg_at<96>(acc, hbase + 160*64, WLs + 672*8, rq, bq); break;
        }
      }
#pragma unroll
      for (int r = 0; r < 4; ++r)
        *(float2*)&REDs[((q * 8 + rq * 4 + r) * 64) + 2 * bq] = make_float2(acc[r][0], acc[r][1]);
      __syncthreads();
      if (tid < 128) {
        int b = tid & 63, u = tid >> 6;
        float g4[4];
#pragma unroll
        for (int g = 0; g < 4; ++g) {
          int slot = g * 2 + u;
          float s = BIs[slot];
#pragma unroll
          for (int qq = 0; qq < 8; ++qq) s += REDs[(qq * 8 + slot) * 64 + b];
          g4[g] = s;
        }
        float iv = sigm(g4[0]), fv = sigm(g4[1]), gv = tanhf(g4[2]), ov = sigm(g4[3]);
        int j = u0 + u, kk = d * 256 + j;
        float c1 = fv * cReg + iv * gv;
        cReg = c1;
        float h1 = ov * tanhf(c1);
        hReg = h1;
        ast(ws + HST_ + ((size_t)(d * 2 + nxt) * 256 + j) * 64 + b, h1);
        if (layer == 0) ws[H1T_ + ((size_t)tt * 512 + kk) * 64 + b] = h1;
        else            ws[ENC_ + ((size_t)b * 512 + kk) * 512 + tt] = h1;
      }
      dbar(dirbar, wgl);   // direction-local relaxed
    }
    if (layer == 0) {  // reset state for layer 1 (own units, both buffers)
      if (tid < 128) {
        int b = tid & 63, u = tid >> 6;
        ast(ws + HST_ + ((size_t)(d * 2 + 0) * 256 + u0 + u) * 64 + b, 0.f);
        ast(ws + HST_ + ((size_t)(d * 2 + 1) * 256 + u0 + u) * 64 + b, 0.f);
        cReg = 0.f;
      }
    }
  }

  // ---------- decoder init: publish h0/c0 (unit k = wg*2+u owned by this WG) ----------
  if (tid < 128) {
    int b = tid & 63, u = tid >> 6;
    int k = wg * 2 + u;
    ast(ws + HDT_ + (size_t)k * 64 + b, hReg);   // buf 0
    ast(ws + CSTD_ + (size_t)k * 64 + b, cReg);
  }
  fill_wl(WLs, BIs, Wihd, Whhd, bihd, bhhd, 1088, 512, 512, wg * 2, 1600);
  fullbar(bar, wg);   // ENC bulk stores visible

  const float bp0 = bp[0];
  const int ab = wg >> 2;                 // batch owned for attention
  const int j4 = wg & 3;                  // s-quarter / k-quarter
  unsigned* mb = bar + 4096 + ab * 64;

  for (int t = 0; t < 512; ++t) {
    const int cur = t & 1, nxt = cur ^ 1;

    // ===== Phase A: load h,c; projection of h (=y_{t-1}); scores for s-quarter =====
    HBs[tid] = ald(ws + HDT_ + (size_t)cur * 32768 + (size_t)tid * 64 + ab);
    CBs[tid] = ald(ws + CSTD_ + (size_t)tid * 64 + ab);
    __syncthreads();

    float pv = HBs[tid] * Wp[tid];
#pragma unroll
    for (int o = 1; o <= 32; o <<= 1) pv += __shfl_xor(pv, o);
    if (lane == 0) PRJ[w] = pv;

    {
      const int kg = tid >> 4, sc = tid & 15;
      float sH[8] = {0,0,0,0,0,0,0,0}, sC[8] = {0,0,0,0,0,0,0,0};
      const float* eb = ws + ENC_ + (size_t)ab * 262144 + j4 * 128 + sc * 8;
#pragma unroll 4
      for (int i = 0; i < 16; ++i) {
        int k = kg * 16 + i;
        const float* row = eb + (size_t)k * 512;
        float4 a = *(const float4*)row;
        float4 c4 = *(const float4*)(row + 4);
        float hk = HBs[k], ck = CBs[k];
        sH[0]=fmaf(a.x,hk,sH[0]); sH[1]=fmaf(a.y,hk,sH[1]); sH[2]=fmaf(a.z,hk,sH[2]); sH[3]=fmaf(a.w,hk,sH[3]);
        sH[4]=fmaf(c4.x,hk,sH[4]); sH[5]=fmaf(c4.y,hk,sH[5]); sH[6]=fmaf(c4.z,hk,sH[6]); sH[7]=fmaf(c4.w,hk,sH[7]);
        sC[0]=fmaf(a.x,ck,sC[0]); sC[1]=fmaf(a.y,ck,sC[1]); sC[2]=fmaf(a.z,ck,sC[2]); sC[3]=fmaf(a.w,ck,sC[3]);
        sC[4]=fmaf(c4.x,ck,sC[4]); sC[5]=fmaf(c4.y,ck,sC[5]); sC[6]=fmaf(c4.z,ck,sC[6]); sC[7]=fmaf(c4.w,ck,sC[7]);
      }
#pragma unroll
      for (int o = 16; o <= 32; o <<= 1)
#pragma unroll
        for (int r = 0; r < 8; ++r) { sH[r] += __shfl_xor(sH[r], o); sC[r] += __shfl_xor(sC[r], o); }
      if (lane < 16) {
#pragma unroll
        for (int r = 0; r < 8; ++r) {
          REDs[(w * 16 + lane) * 8 + r] = sH[r];
          REDs[1024 + (w * 16 + lane) * 8 + r] = sC[r];
        }
      }
    }
    __syncthreads();
    if (tid < 128) {
      const int sc2 = tid >> 3, r = tid & 7;
      float th = 0.f, tc = 0.f;
#pragma unroll
      for (int ww = 0; ww < 8; ++ww) {
        th += REDs[(ww * 16 + sc2) * 8 + r];
        tc += REDs[1024 + (ww * 16 + sc2) * 8 + r];
      }
      ast(ws + SCO_ + ((size_t)ab * 2 + 0) * 512 + j4 * 128 + tid, th);
      ast(ws + SCO_ + ((size_t)ab * 2 + 1) * 512 + j4 * 128 + tid, tc);
      if (tid == 0 && j4 == 0 && t > 0) {
        float v = bp0;
#pragma unroll
        for (int ww = 0; ww < 8; ++ww) v += PRJ[ww];
        out[(size_t)ab * 512 + (t - 1)] = v;
      }
    }
    mbar4(mb);

    // ===== softmax over full 512 (replicated per WG) =====
    {
      float vh = ald(ws + SCO_ + ((size_t)ab * 2 + 0) * 512 + tid);
      float vc = ald(ws + SCO_ + ((size_t)ab * 2 + 1) * 512 + tid);
      float mh = vh, mc = vc;
#pragma unroll
      for (int o = 1; o <= 32; o <<= 1) { mh = fmaxf(mh, __shfl_xor(mh, o)); mc = fmaxf(mc, __shfl_xor(mc, o)); }
      if (lane == 0) { REDs[w] = mh; REDs[8 + w] = mc; }
      __syncthreads();
      mh = REDs[0]; mc = REDs[8];
#pragma unroll
      for (int ww = 1; ww < 8; ++ww) { mh = fmaxf(mh, REDs[ww]); mc = fmaxf(mc, REDs[8 + ww]); }
      float eh = expf(vh - mh), ec = expf(vc - mc);
      float zh = eh, zc = ec;
#pragma unroll
      for (int o = 1; o <= 32; o <<= 1) { zh += __shfl_xor(zh, o); zc += __shfl_xor(zc, o); }
      if (lane == 0) { REDs[16 + w] = zh; REDs[24 + w] = zc; }
      __syncthreads();
      zh = 0.f; zc = 0.f;
#pragma unroll
      for (int ww = 0; ww < 8; ++ww) { zh += REDs[16 + ww]; zc += REDs[24 + ww]; }
      WHs[tid] = eh / zh;
      WCs[tid] = ec / zc;
    }
    __syncthreads();

    // ===== ctx for k-quarter j4: ctx[k] = sum_s w[s]*enc[k][s] =====
    {
      const int row = tid >> 2, seg = tid & 3;
      const int k = j4 * 128 + row;
      const float* er = ws + ENC_ + (size_t)ab * 262144 + (size_t)k * 512 + seg * 128;
      const float* wh = WHs + seg * 128;
      const float* wc = WCs + seg * 128;
      float aH = 0.f, aC = 0.f;
#pragma unroll 8
      for (int i = 0; i < 32; ++i) {
        float4 e = *(const float4*)(er + i * 4);
        aH += e.x*wh[i*4] + e.y*wh[i*4+1] + e.z*wh[i*4+2] + e.w*wh[i*4+3];
        aC += e.x*wc[i*4] + e.y*wc[i*4+1] + e.z*wc[i*4+2] + e.w*wc[i*4+3];
      }
      aH += __shfl_xor(aH, 1); aH += __shfl_xor(aH, 2);
      aC += __shfl_xor(aC, 1); aC += __shfl_xor(aC, 2);
      if (seg == 0) {
        ast(ws + CTXD_ + (size_t)k * 64 + ab, aH);
        ast(ws + CTXD_ + (size_t)(512 + k) * 64 + ab, aC);
      }
    }
    gbar(bar, wg);   // G2: all ctx published

    // ===== Phase C: gate GEMM (K=1600) + pointwise =====
    {
      float acc[4][2] = {{0.f,0.f},{0.f,0.f},{0.f,0.f},{0.f,0.f}};
      const float* xb  = ws + XT_  + (size_t)t * 4096;
      const float* ctx = ws + CTXD_;
      const float* hdb = ws + HDT_ + (size_t)cur * 32768;
      switch (q) {
        case 0: dot_seg<64>(acc, xb, WLs, rq, bq);
                dot_seg_at<136>(acc, ctx, WLs + 64*8, rq, bq); break;
        case 1: dot_seg_at<200>(acc, ctx + 136*64, WLs + 200*8, rq, bq); break;
        case 2: dot_seg_at<200>(acc, ctx + 336*64, WLs + 400*8, rq, bq); break;
        case 3: dot_seg_at<200>(acc, ctx + 536*64, WLs + 600*8, rq, bq); break;
        case 4: dot_seg_at<200>(acc, ctx + 736*64, WLs + 800*8, rq, bq); break;
        case 5: dot_seg_at<88>(acc, ctx + 936*64, WLs + 1000*8, rq, bq);
                dot_seg_at<112>(acc, hdb, WLs + 1088*8, rq, bq); break;
        case 6: dot_seg_at<200>(acc, hdb + 112*64, WLs + 1200*8, rq, bq); break;
        default:dot_seg_at<200>(acc, hdb + 312*64, WLs + 1400*8, rq, bq); break;
      }
#pragma unroll
      for (int r = 0; r < 4; ++r)
        *(float2*)&REDs[((q * 8 + rq * 4 + r) * 64) + 2 * bq] = make_float2(acc[r][0], acc[r][1]);
      __syncthreads();
      if (tid < 128) {
        int b = tid & 63, u = tid >> 6;
        float g4[4];
#pragma unroll
        for (int g = 0; g < 4; ++g) {
          int slot = g * 2 + u;
          float s = BIs[slot];
#pragma unroll
          for (int qq = 0; qq < 8; ++qq) s += REDs[(qq * 8 + slot) * 64 + b];
          g4[g] = s;
        }
        float iv = sigm(g4[0]), fv = sigm(g4[1]), gv = tanhf(g4[2]), ov = sigm(g4[3]);
        int k = wg * 2 + u;
        float c1 = fv * cReg + iv * gv;
        cReg = c1;
        float h1 = ov * tanhf(c1);
        ast(ws + CSTD_ + (size_t)k * 64 + b, c1);
        ast(ws + HDT_ + (size_t)nxt * 32768 + (size_t)k * 64 + b, h1);
      }
    }
    gbar(bar, wg);   // G1: h,c for next step published
  }

  // ---------- epilogue: out[b][511] from final h (buf 0) ----------
  if (j4 == 0) {
    HBs[tid] = ald(ws + HDT_ + (size_t)tid * 64 + ab);
    __syncthreads();
    float pv = HBs[tid] * Wp[tid];
#pragma unroll
    for (int o = 1; o <= 32; o <<= 1) pv += __shfl_xor(pv, o);
    if (lane == 0) PRJ[w] = pv;
    __syncthreads();
    if (tid == 0) {
      float v = bp0;
#pragma unroll
      for (int ww = 0; ww < 8; ++ww) v += PRJ[ww];
      out[(size_t)ab * 512 + 511] = v;
    }
  }
}

extern "C" void kernel_launch(void* const* d_in, const int* in_sizes, int n_in,
                              void* d_out, int out_size, void* d_ws, size_t ws_size,
                              hipStream_t stream) {
  const float* x    = (const float*)d_in[0];
  const float* Wih0 = (const float*)d_in[1];
  const float* Whh0 = (const float*)d_in[2];
  const float* bih0 = (const float*)d_in[3];
  const float* bhh0 = (const float*)d_in[4];
  const float* Wih1 = (const float*)d_in[5];
  const float* Whh1 = (const float*)d_in[6];
  const float* bih1 = (const float*)d_in[7];
  const float* bhh1 = (const float*)d_in[8];
  const float* Wihd = (const float*)d_in[9];
  const float* Whhd = (const float*)d_in[10];
  const float* bihd = (const float*)d_in[11];
  const float* bhhd = (const float*)d_in[12];
  const float* Wp   = (const float*)d_in[13];
  const float* bp   = (const float*)d_in[14];
  float* out = (float*)d_out;
  float* ws  = (float*)d_ws;
  (void)ws_size; (void)n_in; (void)in_sizes;

  // zero barrier counters (monotonic; re-zeroed each launch/replay)
  hipMemsetAsync(d_ws, 0, 8192 * 4, stream);
  hipMemsetAsync(d_out, 0, (size_t)out_size * sizeof(float), stream);

  hipFuncSetAttribute((const void*)seq2seq_ker,
                      hipFuncAttributeMaxDynamicSharedMemorySize, SMEM_F * 4);

  hipLaunchKernelGGL(seq2seq_ker, dim3(NWG), dim3(NT), SMEM_F * 4, stream,
                     x, Wih0, Whh0, bih0, bhh0, Wih1, Whh1, bih1, bhh1,
                     Wihd, Whhd, bihd, bhhd, Wp, bp, out, ws);
}

// Round 4
// 55472.485 us; speedup vs baseline: 1.9992x; 1.1202x over previous
//
#include <hip/hip_runtime.h>
#include <cmath>

#define NWG 256
#define NT  512

// ---------------- workspace layout (float offsets) ----------------
static constexpr size_t XT_  = 8192;                        // xT[t][k][b] 512*64*64
static constexpr size_t H1T_ = XT_  + (size_t)512*64*64;    // H1T[t][k][b] 512*512*64
static constexpr size_t ENC_ = H1T_ + (size_t)512*512*64;   // ENC[b][k][s] 64*512*512
static constexpr size_t HST_ = ENC_ + (size_t)64*512*512;   // enc h [d][buf][j][b] 2*2*256*64
static constexpr size_t HDT_ = HST_ + (size_t)2*2*256*64;   // dec h [buf][k][b] 2*512*64
static constexpr size_t HDB_ = HDT_ + (size_t)2*512*64;     // dec h [buf][b][k] 2*64*512
static constexpr size_t CDB_ = HDB_ + (size_t)2*64*512;     // dec c [b][k] 64*512
static constexpr size_t CTXD_= CDB_ + (size_t)64*512;       // ctx [hc*512+k][b] 1024*64
static constexpr size_t SCO_ = CTXD_+ (size_t)1024*64;      // scores [b][hc][s] 64*2*512

// ---------------- LDS layout (float offsets) ----------------
static constexpr int WL_O  = 0;              // weights [k][8 slots] (dec K=1600) 12800
static constexpr int RED_O = 12800;          // reduce scratch 4096
static constexpr int HB_O  = RED_O + 4096;   // h[512]
static constexpr int CB_O  = HB_O + 512;     // c[512]
static constexpr int WH_O  = CB_O + 512;     // softmax wts h [512]
static constexpr int WC_O  = WH_O + 512;     // softmax wts c [512]
static constexpr int PRJ_O = WC_O + 512;     // projection partials [8]
static constexpr int BI_O  = PRJ_O + 8;      // bias [8]
static constexpr int SMEM_F = BI_O + 8;      // 18960 floats = 75840 B

__device__ __forceinline__ float sigm(float v) { return 1.f / (1.f + expf(-v)); }

__device__ __forceinline__ unsigned uld(unsigned* p) {
  return __hip_atomic_load(p, __ATOMIC_RELAXED, __HIP_MEMORY_SCOPE_AGENT);
}
__device__ __forceinline__ unsigned uadd(unsigned* p) {
  return __hip_atomic_fetch_add(p, 1u, __ATOMIC_RELAXED, __HIP_MEMORY_SCOPE_AGENT);
}
__device__ __forceinline__ void ast(float* p, float v) {
  __hip_atomic_store(p, v, __ATOMIC_RELAXED, __HIP_MEMORY_SCOPE_AGENT);
}
// acquire fence at agent scope -> buffer_inv (L1/L2 invalidate): subsequent NORMAL
// loads see LLC-coherent data. Executed POST-wait only (all local WGs arrived, so
// no concurrent reader can re-cache stale lines between inv and our loads).
__device__ __forceinline__ void acqf() { __builtin_amdgcn_fence(__ATOMIC_ACQUIRE, "agent"); }
__device__ __forceinline__ void relf() { __builtin_amdgcn_fence(__ATOMIC_RELEASE, "agent"); }

// Global 256-WG relaxed barrier: monotonic 3-level tree.
// bar layout (uints): gen@0, leaf l @32+l*32 (32 leaves x8), mid m @1056+m*32 (4 x8), root @1184 (x4).
__device__ __forceinline__ void gbar(unsigned* bar, int wg) {
  __syncthreads();   // vmcnt(0) drain: prior (atomic) stores complete/visible
  if (threadIdx.x == 0) {
    unsigned g = uld(bar);
    if (((uadd(&bar[32 + (wg >> 3) * 32]) + 1) & 7) == 0)
      if (((uadd(&bar[1056 + (wg >> 6) * 32]) + 1) & 7) == 0)
        if (((uadd(&bar[1184]) + 1) & 3) == 0)
          uadd(bar);
    while (uld(bar) == g) __builtin_amdgcn_s_sleep(1);
    acqf();
  }
  __syncthreads();
}

// Phase-boundary barrier: release (wbl2) before arrival for bulk NORMAL stores.
__device__ __forceinline__ void fullbar(unsigned* bar, int wg) {
  __syncthreads();
  if (threadIdx.x == 0) {
    relf();
    unsigned g = uld(bar);
    if (((uadd(&bar[32 + (wg >> 3) * 32]) + 1) & 7) == 0)
      if (((uadd(&bar[1056 + (wg >> 6) * 32]) + 1) & 7) == 0)
        if (((uadd(&bar[1184]) + 1) & 3) == 0)
          uadd(bar);
    while (uld(bar) == g) __builtin_amdgcn_s_sleep(2);
    acqf();
  }
  __syncthreads();
}

// Direction-local 128-WG relaxed barrier: 2-level (16 leaves x8, root x16).
__device__ __forceinline__ void dbar(unsigned* base, int wgl) {
  __syncthreads();
  if (threadIdx.x == 0) {
    unsigned g = uld(base);
    if (((uadd(&base[32 + (wgl >> 3) * 32]) + 1) & 7) == 0)
      if (((uadd(&base[544]) + 1) & 15) == 0)
        uadd(base);
    while (uld(base) == g) __builtin_amdgcn_s_sleep(1);
    acqf();
  }
  __syncthreads();
}

// 4-WG relaxed minibar: gen@0, cnt@32.
__device__ __forceinline__ void mbar4(unsigned* base) {
  __syncthreads();
  if (threadIdx.x == 0) {
    unsigned g = uld(base);
    if (((uadd(&base[32]) + 1) & 3) == 0) uadd(base);
    while (uld(base) == g) __builtin_amdgcn_s_sleep(1);
    acqf();
  }
  __syncthreads();
}

// Gate-GEMM K-segment, normal vectorized loads. Lane: 4 slots (rq) x 2 batches (bq).
template<int N>
__device__ __forceinline__ void dot_seg(float (&acc)[4][2], const float* kb,
                                        const float* wl, int rq, int bq) {
#pragma unroll 16
  for (int i = 0; i < N; ++i) {
    float2 hv = *(const float2*)(kb + (size_t)i * 64 + 2 * bq);
    float4 wv = *(const float4*)(wl + i * 8 + rq * 4);
    acc[0][0] = fmaf(wv.x, hv.x, acc[0][0]); acc[0][1] = fmaf(wv.x, hv.y, acc[0][1]);
    acc[1][0] = fmaf(wv.y, hv.x, acc[1][0]); acc[1][1] = fmaf(wv.y, hv.y, acc[1][1]);
    acc[2][0] = fmaf(wv.z, hv.x, acc[2][0]); acc[2][1] = fmaf(wv.z, hv.y, acc[2][1]);
    acc[3][0] = fmaf(wv.w, hv.x, acc[3][0]); acc[3][1] = fmaf(wv.w, hv.y, acc[3][1]);
  }
}

// Load this WG's 8 gate rows (2 units x 4 gates, slot = g*2+u) into LDS, plus bias.
__device__ void fill_wl(float* WLs, float* BIs,
                        const float* Wih, const float* Whh,
                        const float* bih, const float* bhh,
                        int KI, int KH, int gstride, int u0, int K) {
  for (int idx = threadIdx.x; idx < K * 8; idx += NT) {
    int k = idx >> 3, slot = idx & 7;
    int row = (slot >> 1) * gstride + u0 + (slot & 1);
    WLs[k * 8 + slot] = (k < KI) ? Wih[(size_t)row * KI + k]
                                 : Whh[(size_t)row * KH + (k - KI)];
  }
  if (threadIdx.x < 8) {
    int row = ((int)threadIdx.x >> 1) * gstride + u0 + ((int)threadIdx.x & 1);
    BIs[threadIdx.x] = bih[row] + bhh[row];
  }
  __syncthreads();
}

extern "C" __global__ void __launch_bounds__(NT, 1)
seq2seq_ker(const float* __restrict__ x,
            const float* __restrict__ Wih0, const float* __restrict__ Whh0,
            const float* __restrict__ bih0, const float* __restrict__ bhh0,
            const float* __restrict__ Wih1, const float* __restrict__ Whh1,
            const float* __restrict__ bih1, const float* __restrict__ bhh1,
            const float* __restrict__ Wihd, const float* __restrict__ Whhd,
            const float* __restrict__ bihd, const float* __restrict__ bhhd,
            const float* __restrict__ Wp,   const float* __restrict__ bp,
            float* out, float* ws) {
  extern __shared__ float smem[];
  float* WLs = smem + WL_O;
  float* REDs = smem + RED_O;
  float* HBs = smem + HB_O;
  float* CBs = smem + CB_O;
  float* WHs = smem + WH_O;
  float* WCs = smem + WC_O;
  float* PRJ = smem + PRJ_O;
  float* BIs = smem + BI_O;

  unsigned* bar = (unsigned*)ws;
  const int tid = threadIdx.x;
  const int wg  = blockIdx.x;
  const int gtid = wg * NT + tid;
  const int lane = tid & 63, q = tid >> 6, w = q;
  const int rq = lane & 1, bq = lane >> 1;

  // ---------- prep: transpose x -> xT[t][k][b] (read-coalesced); zero enc h ----------
  for (size_t i = gtid; i < (size_t)512 * 64 * 64; i += (size_t)NWG * NT) {
    int k = (int)(i & 63), t = (int)((i >> 6) & 511), b = (int)(i >> 15);
    ws[XT_ + (size_t)t * 4096 + k * 64 + b] = x[i];
  }
  if (gtid < 65536) ast(ws + HST_ + gtid, 0.f);

  // ---------- encoder: 2 layers ----------
  const int d  = wg >> 7;                 // direction
  const int u0 = (wg & 127) * 2;          // this WG's 2 hidden units within dir
  const int wgl = wg & 127;
  unsigned* dirbar = bar + 2048 + d * 1024;

  float cReg = 0.f, hReg = 0.f;

  for (int layer = 0; layer < 2; ++layer) {
    if (layer == 0)
      fill_wl(WLs, BIs, Wih0 + (size_t)d * 1024 * 64,  Whh0 + (size_t)d * 1024 * 256,
              bih0 + d * 1024, bhh0 + d * 1024, 64, 256, 256, u0, 320);
    else
      fill_wl(WLs, BIs, Wih1 + (size_t)d * 1024 * 512, Whh1 + (size_t)d * 1024 * 256,
              bih1 + d * 1024, bhh1 + d * 1024, 512, 256, 256, u0, 768);
    fullbar(bar, wg);   // XT / H1T bulk data + zeroed state visible

    for (int t = 0; t < 512; ++t) {
      const int cur = t & 1, nxt = cur ^ 1;
      const int tt = d ? (511 - t) : t;
      float acc[4][2] = {{0.f,0.f},{0.f,0.f},{0.f,0.f},{0.f,0.f}};
      const float* hbase = ws + HST_ + ((size_t)(d * 2 + cur) * 256) * 64;
      if (layer == 0) {
        const float* xb = ws + XT_ + (size_t)tt * 4096;
        switch (q) {
          case 0: dot_seg<40>(acc, xb, WLs, rq, bq); break;
          case 1: dot_seg<24>(acc, xb + 40*64, WLs + 40*8, rq, bq);
                  dot_seg<16>(acc, hbase, WLs + 64*8, rq, bq); break;
          case 2: dot_seg<40>(acc, hbase + 16*64,  WLs + 80*8,  rq, bq); break;
          case 3: dot_seg<40>(acc, hbase + 56*64,  WLs + 120*8, rq, bq); break;
          case 4: dot_seg<40>(acc, hbase + 96*64,  WLs + 160*8, rq, bq); break;
          case 5: dot_seg<40>(acc, hbase + 136*64, WLs + 200*8, rq, bq); break;
          case 6: dot_seg<40>(acc, hbase + 176*64, WLs + 240*8, rq, bq); break;
          default:dot_seg<40>(acc, hbase + 216*64, WLs + 280*8, rq, bq); break;
        }
      } else {
        const float* ib = ws + H1T_ + (size_t)tt * 512 * 64;
        switch (q) {
          case 0: dot_seg<96>(acc, ib,          WLs,         rq, bq); break;
          case 1: dot_seg<96>(acc, ib + 96*64,  WLs + 96*8,  rq, bq); break;
          case 2: dot_seg<96>(acc, ib + 192*64, WLs + 192*8, rq, bq); break;
          case 3: dot_seg<96>(acc, ib + 288*64, WLs + 288*8, rq, bq); break;
          case 4: dot_seg<96>(acc, ib + 384*64, WLs + 384*8, rq, bq); break;
          case 5: dot_seg<32>(acc, ib + 480*64, WLs + 480*8, rq, bq);
                  dot_seg<64>(acc, hbase, WLs + 512*8, rq, bq); break;
          case 6: dot_seg<96>(acc, hbase + 64*64,  WLs + 576*8, rq, bq); break;
          default:dot_seg<96>(acc, hbase + 160*64, WLs + 672*8, rq, bq); break;
        }
      }
#pragma unroll
      for (int r = 0; r < 4; ++r)
        *(float2*)&REDs[((q * 8 + rq * 4 + r) * 64) + 2 * bq] = make_float2(acc[r][0], acc[r][1]);
      __syncthreads();
      if (tid < 128) {
        int b = tid & 63, u = tid >> 6;
        float g4[4];
#pragma unroll
        for (int g = 0; g < 4; ++g) {
          int slot = g * 2 + u;
          float s = BIs[slot];
#pragma unroll
          for (int qq = 0; qq < 8; ++qq) s += REDs[(qq * 8 + slot) * 64 + b];
          g4[g] = s;
        }
        float iv = sigm(g4[0]), fv = sigm(g4[1]), gv = tanhf(g4[2]), ov = sigm(g4[3]);
        int j = u0 + u, kk = d * 256 + j;
        float c1 = fv * cReg + iv * gv;
        cReg = c1;
        float h1 = ov * tanhf(c1);
        hReg = h1;
        ast(ws + HST_ + ((size_t)(d * 2 + nxt) * 256 + j) * 64 + b, h1);
        if (layer == 0) ws[H1T_ + ((size_t)tt * 512 + kk) * 64 + b] = h1;
        else            ws[ENC_ + ((size_t)b * 512 + kk) * 512 + tt] = h1;
      }
      dbar(dirbar, wgl);
    }
    if (layer == 0) {  // reset own state for layer 1 (post-dbar: nobody reading)
      if (tid < 128) {
        int b = tid & 63, u = tid >> 6;
        ast(ws + HST_ + ((size_t)(d * 2 + 0) * 256 + u0 + u) * 64 + b, 0.f);
        ast(ws + HST_ + ((size_t)(d * 2 + 1) * 256 + u0 + u) * 64 + b, 0.f);
        cReg = 0.f;
      }
    }
  }

  // ---------- decoder init: publish h0/c0 (unit k = wg*2+u owned by this WG) ----------
  if (tid < 128) {
    int b = tid & 63, u = tid >> 6;
    int k = wg * 2 + u;
    ast(ws + HDT_ + (size_t)k * 64 + b, hReg);           // buf 0, [k][b]
    ast(ws + HDB_ + (size_t)b * 512 + k, hReg);          // buf 0, [b][k]
    ast(ws + CDB_ + (size_t)b * 512 + k, cReg);
  }
  fill_wl(WLs, BIs, Wihd, Whhd, bihd, bhhd, 1088, 512, 512, wg * 2, 1600);
  fullbar(bar, wg);   // ENC bulk stores visible

  const float bp0 = bp[0];
  const int ab = wg >> 2;                 // batch owned for attention
  const int j4 = wg & 3;                  // s-quarter / k-quarter
  unsigned* mb = bar + 4096 + ab * 64;

  for (int t = 0; t < 512; ++t) {
    const int cur = t & 1, nxt = cur ^ 1;

    // ===== Phase A: load h,c (coalesced [b][k]); projection; scores for s-quarter =====
    HBs[tid] = ws[HDB_ + (size_t)cur * 32768 + (size_t)ab * 512 + tid];
    CBs[tid] = ws[CDB_ + (size_t)ab * 512 + tid];
    __syncthreads();

    float pv = HBs[tid] * Wp[tid];
#pragma unroll
    for (int o = 1; o <= 32; o <<= 1) pv += __shfl_xor(pv, o);
    if (lane == 0) PRJ[w] = pv;

    {
      const int kg = tid >> 4, sc = tid & 15;
      float sH[8] = {0,0,0,0,0,0,0,0}, sC[8] = {0,0,0,0,0,0,0,0};
      const float* eb = ws + ENC_ + (size_t)ab * 262144 + j4 * 128 + sc * 8;
#pragma unroll 4
      for (int i = 0; i < 16; ++i) {
        int k = kg * 16 + i;
        const float* row = eb + (size_t)k * 512;
        float4 a = *(const float4*)row;
        float4 c4 = *(const float4*)(row + 4);
        float hk = HBs[k], ck = CBs[k];
        sH[0]=fmaf(a.x,hk,sH[0]); sH[1]=fmaf(a.y,hk,sH[1]); sH[2]=fmaf(a.z,hk,sH[2]); sH[3]=fmaf(a.w,hk,sH[3]);
        sH[4]=fmaf(c4.x,hk,sH[4]); sH[5]=fmaf(c4.y,hk,sH[5]); sH[6]=fmaf(c4.z,hk,sH[6]); sH[7]=fmaf(c4.w,hk,sH[7]);
        sC[0]=fmaf(a.x,ck,sC[0]); sC[1]=fmaf(a.y,ck,sC[1]); sC[2]=fmaf(a.z,ck,sC[2]); sC[3]=fmaf(a.w,ck,sC[3]);
        sC[4]=fmaf(c4.x,ck,sC[4]); sC[5]=fmaf(c4.y,ck,sC[5]); sC[6]=fmaf(c4.z,ck,sC[6]); sC[7]=fmaf(c4.w,ck,sC[7]);
      }
#pragma unroll
      for (int o = 16; o <= 32; o <<= 1)
#pragma unroll
        for (int r = 0; r < 8; ++r) { sH[r] += __shfl_xor(sH[r], o); sC[r] += __shfl_xor(sC[r], o); }
      if (lane < 16) {   // stride-9 layout: bank-conflict-free
#pragma unroll
        for (int r = 0; r < 8; ++r) {
          REDs[(w * 16 + lane) * 9 + r] = sH[r];
          REDs[1152 + (w * 16 + lane) * 9 + r] = sC[r];
        }
      }
    }
    __syncthreads();
    if (tid < 128) {
      const int sc2 = tid >> 3, r = tid & 7;
      float th = 0.f, tc = 0.f;
#pragma unroll
      for (int ww = 0; ww < 8; ++ww) {
        th += REDs[(ww * 16 + sc2) * 9 + r];
        tc += REDs[1152 + (ww * 16 + sc2) * 9 + r];
      }
      ast(ws + SCO_ + ((size_t)ab * 2 + 0) * 512 + j4 * 128 + tid, th);
      ast(ws + SCO_ + ((size_t)ab * 2 + 1) * 512 + j4 * 128 + tid, tc);
      if (tid == 0 && j4 == 0 && t > 0) {
        float v = bp0;
#pragma unroll
        for (int ww = 0; ww < 8; ++ww) v += PRJ[ww];
        out[(size_t)ab * 512 + (t - 1)] = v;
      }
    }
    mbar4(mb);

    // ===== softmax over full 512 (replicated per WG; normal loads post-inv) =====
    {
      float vh = ws[SCO_ + ((size_t)ab * 2 + 0) * 512 + tid];
      float vc = ws[SCO_ + ((size_t)ab * 2 + 1) * 512 + tid];
      float mh = vh, mc = vc;
#pragma unroll
      for (int o = 1; o <= 32; o <<= 1) { mh = fmaxf(mh, __shfl_xor(mh, o)); mc = fmaxf(mc, __shfl_xor(mc, o)); }
      if (lane == 0) { REDs[w] = mh; REDs[8 + w] = mc; }
      __syncthreads();
      mh = REDs[0]; mc = REDs[8];
#pragma unroll
      for (int ww = 1; ww < 8; ++ww) { mh = fmaxf(mh, REDs[ww]); mc = fmaxf(mc, REDs[8 + ww]); }
      float eh = expf(vh - mh), ec = expf(vc - mc);
      float zh = eh, zc = ec;
#pragma unroll
      for (int o = 1; o <= 32; o <<= 1) { zh += __shfl_xor(zh, o); zc += __shfl_xor(zc, o); }
      if (lane == 0) { REDs[16 + w] = zh; REDs[24 + w] = zc; }
      __syncthreads();
      zh = 0.f; zc = 0.f;
#pragma unroll
      for (int ww = 0; ww < 8; ++ww) { zh += REDs[16 + ww]; zc += REDs[24 + ww]; }
      WHs[tid] = eh / zh;
      WCs[tid] = ec / zc;
    }
    __syncthreads();

    // ===== ctx for k-quarter j4: ctx[k] = sum_s w[s]*enc[k][s] =====
    {
      const int row = tid >> 2, seg = tid & 3;
      const int k = j4 * 128 + row;
      const float* er = ws + ENC_ + (size_t)ab * 262144 + (size_t)k * 512 + seg * 128;
      const float* wh = WHs + seg * 128;
      const float* wc = WCs + seg * 128;
      float aH = 0.f, aC = 0.f;
#pragma unroll 8
      for (int i = 0; i < 32; ++i) {
        float4 e = *(const float4*)(er + i * 4);
        aH += e.x*wh[i*4] + e.y*wh[i*4+1] + e.z*wh[i*4+2] + e.w*wh[i*4+3];
        aC += e.x*wc[i*4] + e.y*wc[i*4+1] + e.z*wc[i*4+2] + e.w*wc[i*4+3];
      }
      aH += __shfl_xor(aH, 1); aH += __shfl_xor(aH, 2);
      aC += __shfl_xor(aC, 1); aC += __shfl_xor(aC, 2);
      if (seg == 0) {
        ast(ws + CTXD_ + (size_t)k * 64 + ab, aH);
        ast(ws + CTXD_ + (size_t)(512 + k) * 64 + ab, aC);
      }
    }
    gbar(bar, wg);   // G2: all ctx published

    // ===== Phase C: gate GEMM (K=1600, all normal vectorized loads) =====
    {
      float acc[4][2] = {{0.f,0.f},{0.f,0.f},{0.f,0.f},{0.f,0.f}};
      const float* xb  = ws + XT_  + (size_t)t * 4096;
      const float* ctx = ws + CTXD_;
      const float* hdb = ws + HDT_ + (size_t)cur * 32768;
      switch (q) {
        case 0: dot_seg<64>(acc, xb, WLs, rq, bq);
                dot_seg<136>(acc, ctx, WLs + 64*8, rq, bq); break;
        case 1: dot_seg<200>(acc, ctx + 136*64, WLs + 200*8, rq, bq); break;
        case 2: dot_seg<200>(acc, ctx + 336*64, WLs + 400*8, rq, bq); break;
        case 3: dot_seg<200>(acc, ctx + 536*64, WLs + 600*8, rq, bq); break;
        case 4: dot_seg<200>(acc, ctx + 736*64, WLs + 800*8, rq, bq); break;
        case 5: dot_seg<88>(acc, ctx + 936*64, WLs + 1000*8, rq, bq);
                dot_seg<112>(acc, hdb, WLs + 1088*8, rq, bq); break;
        case 6: dot_seg<200>(acc, hdb + 112*64, WLs + 1200*8, rq, bq); break;
        default:dot_seg<200>(acc, hdb + 312*64, WLs + 1400*8, rq, bq); break;
      }
#pragma unroll
      for (int r = 0; r < 4; ++r)
        *(float2*)&REDs[((q * 8 + rq * 4 + r) * 64) + 2 * bq] = make_float2(acc[r][0], acc[r][1]);
      __syncthreads();
      if (tid < 128) {
        int b = tid & 63, u = tid >> 6;
        float g4[4];
#pragma unroll
        for (int g = 0; g < 4; ++g) {
          int slot = g * 2 + u;
          float s = BIs[slot];
#pragma unroll
          for (int qq = 0; qq < 8; ++qq) s += REDs[(qq * 8 + slot) * 64 + b];
          g4[g] = s;
        }
        float iv = sigm(g4[0]), fv = sigm(g4[1]), gv = tanhf(g4[2]), ov = sigm(g4[3]);
        int k = wg * 2 + u;
        float c1 = fv * cReg + iv * gv;
        cReg = c1;
        float h1 = ov * tanhf(c1);
        ast(ws + CDB_ + (size_t)b * 512 + k, c1);
        ast(ws + HDT_ + (size_t)nxt * 32768 + (size_t)k * 64 + b, h1);
        ast(ws + HDB_ + (size_t)nxt * 32768 + (size_t)b * 512 + k, h1);
      }
    }
    gbar(bar, wg);   // G1: h,c for next step published
  }

  // ---------- epilogue: out[b][511] from final h (buf 0) ----------
  if (j4 == 0) {
    HBs[tid] = ws[HDB_ + (size_t)ab * 512 + tid];
    __syncthreads();
    float pv = HBs[tid] * Wp[tid];
#pragma unroll
    for (int o = 1; o <= 32; o <<= 1) pv += __shfl_xor(pv, o);
    if (lane == 0) PRJ[w] = pv;
    __syncthreads();
    if (tid == 0) {
      float v = bp0;
#pragma unroll
      for (int ww = 0; ww < 8; ++ww) v += PRJ[ww];
      out[(size_t)ab * 512 + 511] = v;
    }
  }
}

extern "C" void kernel_launch(void* const* d_in, const int* in_sizes, int n_in,
                              void* d_out, int out_size, void* d_ws, size_t ws_size,
                              hipStream_t stream) {
  const float* x    = (const float*)d_in[0];
  const float* Wih0 = (const float*)d_in[1];
  const float* Whh0 = (const float*)d_in[2];
  const float* bih0 = (const float*)d_in[3];
  const float* bhh0 = (const float*)d_in[4];
  const float* Wih1 = (const float*)d_in[5];
  const float* Whh1 = (const float*)d_in[6];
  const float* bih1 = (const float*)d_in[7];
  const float* bhh1 = (const float*)d_in[8];
  const float* Wihd = (const float*)d_in[9];
  const float* Whhd = (const float*)d_in[10];
  const float* bihd = (const float*)d_in[11];
  const float* bhhd = (const float*)d_in[12];
  const float* Wp   = (const float*)d_in[13];
  const float* bp   = (const float*)d_in[14];
  float* out = (float*)d_out;
  float* ws  = (float*)d_ws;
  (void)ws_size; (void)n_in; (void)in_sizes;

  // zero barrier counters (monotonic; re-zeroed each launch/replay) and output
  hipMemsetAsync(d_ws, 0, 8192 * 4, stream);
  hipMemsetAsync(d_out, 0, (size_t)out_size * sizeof(float), stream);

  hipFuncSetAttribute((const void*)seq2seq_ker,
                      hipFuncAttributeMaxDynamicSharedMemorySize, SMEM_F * 4);

  hipLaunchKernelGGL(seq2seq_ker, dim3(NWG), dim3(NT), SMEM_F * 4, stream,
                     x, Wih0, Whh0, bih0, bhh0, Wih1, Whh1, bih1, bhh1,
                     Wihd, Whhd, bihd, bhhd, Wp, bp, out, ws);
}

// Round 5
// 52746.552 us; speedup vs baseline: 2.1025x; 1.0517x over previous
//
#include <hip/hip_runtime.h>
#include <cmath>

#define NWG 256
#define NT  512

// ---------------- workspace layout (float offsets) ----------------
static constexpr size_t XT_  = 8192;                        // xT[t][k][b] 512*64*64
static constexpr size_t H1T_ = XT_  + (size_t)512*64*64;    // H1T[t][k][b] 512*512*64
static constexpr size_t ENC_ = H1T_ + (size_t)512*512*64;   // ENC[b][k][s] 64*512*512 (f32, written once)
static constexpr size_t HST_ = ENC_ + (size_t)64*512*512;   // enc h [d][buf][j][b] 2*2*256*64
static constexpr size_t HDT_ = HST_ + (size_t)2*2*256*64;   // dec h [buf][k][b] 2*512*64
static constexpr size_t HDB_ = HDT_ + (size_t)2*512*64;     // dec h [buf][b][k] 2*64*512
static constexpr size_t CDB_ = HDB_ + (size_t)2*64*512;     // dec c [b][k] 64*512
static constexpr size_t CTXD_= CDB_ + (size_t)64*512;       // ctx [hc*512+k][b] 1024*64
static constexpr size_t SCO_ = CTXD_+ (size_t)1024*64;      // scores [b][hc][s] 64*2*512
static constexpr size_t PART_= SCO_ + (size_t)64*2*512;     // partial ctx [b][sq][k][2] 64*4*512*2

// ---------------- LDS layout ----------------
// Decoder: [0,131072) ENCL bf16 [512 k][64 dw] XOR-swizzled; [131072,156672) WLD bf16 [1600][8];
// [156672,160768) R4 4KB multi-use; [160768,161280) MISC.
// Encoder reuses [0,~76KB) with the old float offsets (disjoint in time).
static constexpr int SMEM_BYTES = 161280;
static constexpr int WLE_F = 0;        // encoder weights f32 [k][8] (K<=768)
static constexpr int REDE_F = 12800;   // encoder reduce scratch [8][8][64]
static constexpr int BIE_F = 18952;    // encoder bias [8]
static constexpr int WLD_F = 32768;    // /4 of 131072
static constexpr int R4_F  = 39168;    // /4 of 156672 (1024 floats)
static constexpr int MISC_F= 40192;    // /4 of 160768

__device__ __forceinline__ float sigm(float v) { return 1.f / (1.f + expf(-v)); }

__device__ __forceinline__ unsigned short f2bf(float f) {
  unsigned u = __float_as_uint(f);
  u += 0x7fffu + ((u >> 16) & 1u);
  return (unsigned short)(u >> 16);
}
__device__ __forceinline__ float bf2f(unsigned short h) {
  return __uint_as_float((unsigned)h << 16);
}

__device__ __forceinline__ unsigned uld(unsigned* p) {
  return __hip_atomic_load(p, __ATOMIC_RELAXED, __HIP_MEMORY_SCOPE_AGENT);
}
__device__ __forceinline__ unsigned uadd(unsigned* p) {
  return __hip_atomic_fetch_add(p, 1u, __ATOMIC_RELAXED, __HIP_MEMORY_SCOPE_AGENT);
}
__device__ __forceinline__ void ast(float* p, float v) {
  __hip_atomic_store(p, v, __ATOMIC_RELAXED, __HIP_MEMORY_SCOPE_AGENT);
}
__device__ __forceinline__ void acqf() { __builtin_amdgcn_fence(__ATOMIC_ACQUIRE, "agent"); }
__device__ __forceinline__ void relf() { __builtin_amdgcn_fence(__ATOMIC_RELEASE, "agent"); }

// Global 256-WG relaxed barrier: monotonic 3-level tree (acquire-inv after wait).
__device__ __forceinline__ void gbar(unsigned* bar, int wg) {
  __syncthreads();
  if (threadIdx.x == 0) {
    unsigned g = uld(bar);
    if (((uadd(&bar[32 + (wg >> 3) * 32]) + 1) & 7) == 0)
      if (((uadd(&bar[1056 + (wg >> 6) * 32]) + 1) & 7) == 0)
        if (((uadd(&bar[1184]) + 1) & 3) == 0)
          uadd(bar);
    while (uld(bar) == g) __builtin_amdgcn_s_sleep(1);
    acqf();
  }
  __syncthreads();
}

// Phase-boundary barrier: release (bulk normal stores) + acquire.
__device__ __forceinline__ void fullbar(unsigned* bar, int wg) {
  __syncthreads();
  if (threadIdx.x == 0) {
    relf();
    unsigned g = uld(bar);
    if (((uadd(&bar[32 + (wg >> 3) * 32]) + 1) & 7) == 0)
      if (((uadd(&bar[1056 + (wg >> 6) * 32]) + 1) & 7) == 0)
        if (((uadd(&bar[1184]) + 1) & 3) == 0)
          uadd(bar);
    while (uld(bar) == g) __builtin_amdgcn_s_sleep(2);
    acqf();
  }
  __syncthreads();
}

// Direction-local 128-WG relaxed barrier.
__device__ __forceinline__ void dbar(unsigned* base, int wgl) {
  __syncthreads();
  if (threadIdx.x == 0) {
    unsigned g = uld(base);
    if (((uadd(&base[32 + (wgl >> 3) * 32]) + 1) & 7) == 0)
      if (((uadd(&base[544]) + 1) & 15) == 0)
        uadd(base);
    while (uld(base) == g) __builtin_amdgcn_s_sleep(1);
    acqf();
  }
  __syncthreads();
}

// 4-WG relaxed minibar.
__device__ __forceinline__ void mbar4(unsigned* base) {
  __syncthreads();
  if (threadIdx.x == 0) {
    unsigned g = uld(base);
    if (((uadd(&base[32]) + 1) & 3) == 0) uadd(base);
    while (uld(base) == g) __builtin_amdgcn_s_sleep(1);
    acqf();
  }
  __syncthreads();
}

// Encoder gate-GEMM K-segment (f32 weights in LDS). Lane: 4 slots x 2 batches.
template<int N>
__device__ __forceinline__ void dot_seg(float (&acc)[4][2], const float* kb,
                                        const float* wl, int rq, int bq) {
#pragma unroll 16
  for (int i = 0; i < N; ++i) {
    float2 hv = *(const float2*)(kb + (size_t)i * 64 + 2 * bq);
    float4 wv = *(const float4*)(wl + i * 8 + rq * 4);
    acc[0][0] = fmaf(wv.x, hv.x, acc[0][0]); acc[0][1] = fmaf(wv.x, hv.y, acc[0][1]);
    acc[1][0] = fmaf(wv.y, hv.x, acc[1][0]); acc[1][1] = fmaf(wv.y, hv.y, acc[1][1]);
    acc[2][0] = fmaf(wv.z, hv.x, acc[2][0]); acc[2][1] = fmaf(wv.z, hv.y, acc[2][1]);
    acc[3][0] = fmaf(wv.w, hv.x, acc[3][0]); acc[3][1] = fmaf(wv.w, hv.y, acc[3][1]);
  }
}

// Decoder gate-GEMM K-segment (bf16 weights in LDS).
template<int N>
__device__ __forceinline__ void dotw(float (&acc)[4][2], const float* kb,
                                     const unsigned short* wl, int rq, int bq) {
#pragma unroll 16
  for (int i = 0; i < N; ++i) {
    float2 hv = *(const float2*)(kb + (size_t)i * 64 + 2 * bq);
    ushort4 wv = *(const ushort4*)(wl + i * 8 + rq * 4);
    float w0 = bf2f(wv.x), w1 = bf2f(wv.y), w2 = bf2f(wv.z), w3 = bf2f(wv.w);
    acc[0][0] = fmaf(w0, hv.x, acc[0][0]); acc[0][1] = fmaf(w0, hv.y, acc[0][1]);
    acc[1][0] = fmaf(w1, hv.x, acc[1][0]); acc[1][1] = fmaf(w1, hv.y, acc[1][1]);
    acc[2][0] = fmaf(w2, hv.x, acc[2][0]); acc[2][1] = fmaf(w2, hv.y, acc[2][1]);
    acc[3][0] = fmaf(w3, hv.x, acc[3][0]); acc[3][1] = fmaf(w3, hv.y, acc[3][1]);
  }
}

// Encoder: this WG's 8 gate rows (2 units x 4 gates) into LDS f32, plus bias.
__device__ void fill_wl(float* WLs, float* BIs,
                        const float* Wih, const float* Whh,
                        const float* bih, const float* bhh,
                        int KI, int KH, int gstride, int u0, int K) {
  for (int idx = threadIdx.x; idx < K * 8; idx += NT) {
    int k = idx >> 3, slot = idx & 7;
    int row = (slot >> 1) * gstride + u0 + (slot & 1);
    WLs[k * 8 + slot] = (k < KI) ? Wih[(size_t)row * KI + k]
                                 : Whh[(size_t)row * KH + (k - KI)];
  }
  if (threadIdx.x < 8) {
    int row = ((int)threadIdx.x >> 1) * gstride + u0 + ((int)threadIdx.x & 1);
    BIs[threadIdx.x] = bih[row] + bhh[row];
  }
  __syncthreads();
}

// Decoder: same, bf16 weights.
__device__ void fill_wld(unsigned short* wld, float* BIs,
                         const float* Wih, const float* Whh,
                         const float* bih, const float* bhh,
                         int KI, int KH, int gstride, int u0, int K) {
  for (int idx = threadIdx.x; idx < K * 8; idx += NT) {
    int k = idx >> 3, slot = idx & 7;
    int row = (slot >> 1) * gstride + u0 + (slot & 1);
    float w = (k < KI) ? Wih[(size_t)row * KI + k]
                       : Whh[(size_t)row * KH + (k - KI)];
    wld[idx] = f2bf(w);
  }
  if (threadIdx.x < 8) {
    int row = ((int)threadIdx.x >> 1) * gstride + u0 + ((int)threadIdx.x & 1);
    BIs[threadIdx.x] = bih[row] + bhh[row];
  }
  __syncthreads();
}

extern "C" __global__ void __launch_bounds__(NT, 1)
seq2seq_ker(const float* __restrict__ x,
            const float* __restrict__ Wih0, const float* __restrict__ Whh0,
            const float* __restrict__ bih0, const float* __restrict__ bhh0,
            const float* __restrict__ Wih1, const float* __restrict__ Whh1,
            const float* __restrict__ bih1, const float* __restrict__ bhh1,
            const float* __restrict__ Wihd, const float* __restrict__ Whhd,
            const float* __restrict__ bihd, const float* __restrict__ bhhd,
            const float* __restrict__ Wp,   const float* __restrict__ bp,
            float* out, float* ws) {
  extern __shared__ float smem[];
  float* WLe  = smem + WLE_F;
  float* REDe = smem + REDE_F;
  float* BIe  = smem + BIE_F;
  unsigned* encl = (unsigned*)smem;                       // bf16-pair slab (decoder)
  unsigned short* wld = (unsigned short*)(smem + WLD_F);  // decoder weights bf16
  float* r4   = smem + R4_F;                              // 1024-float multi-use
  float* misc = smem + MISC_F;
  float* PRJ  = misc;         // [8]
  float* BId  = misc + 8;     // [8]
  float* SMX  = misc + 16;    // [32]

  unsigned* bar = (unsigned*)ws;
  const int tid = threadIdx.x;
  const int wg  = blockIdx.x;
  const int gtid = wg * NT + tid;
  const int lane = tid & 63, q = tid >> 6, w = q;
  const int rq = lane & 1, bq = lane >> 1;

  // ---------- prep: transpose x -> xT[t][k][b] (read-coalesced); zero enc h ----------
  for (size_t i = gtid; i < (size_t)512 * 64 * 64; i += (size_t)NWG * NT) {
    int k = (int)(i & 63), t = (int)((i >> 6) & 511), b = (int)(i >> 15);
    ws[XT_ + (size_t)t * 4096 + k * 64 + b] = x[i];
  }
  if (gtid < 65536) ast(ws + HST_ + gtid, 0.f);

  // ---------- encoder: 2 layers (unchanged structure) ----------
  const int d  = wg >> 7;
  const int u0 = (wg & 127) * 2;
  const int wgl = wg & 127;
  unsigned* dirbar = bar + 2048 + d * 1024;

  float cReg = 0.f, hReg = 0.f;

  for (int layer = 0; layer < 2; ++layer) {
    if (layer == 0)
      fill_wl(WLe, BIe, Wih0 + (size_t)d * 1024 * 64,  Whh0 + (size_t)d * 1024 * 256,
              bih0 + d * 1024, bhh0 + d * 1024, 64, 256, 256, u0, 320);
    else
      fill_wl(WLe, BIe, Wih1 + (size_t)d * 1024 * 512, Whh1 + (size_t)d * 1024 * 256,
              bih1 + d * 1024, bhh1 + d * 1024, 512, 256, 256, u0, 768);
    fullbar(bar, wg);

    for (int t = 0; t < 512; ++t) {
      const int cur = t & 1, nxt = cur ^ 1;
      const int tt = d ? (511 - t) : t;
      float acc[4][2] = {{0.f,0.f},{0.f,0.f},{0.f,0.f},{0.f,0.f}};
      const float* hbase = ws + HST_ + ((size_t)(d * 2 + cur) * 256) * 64;
      if (layer == 0) {
        const float* xb = ws + XT_ + (size_t)tt * 4096;
        switch (q) {
          case 0: dot_seg<40>(acc, xb, WLe, rq, bq); break;
          case 1: dot_seg<24>(acc, xb + 40*64, WLe + 40*8, rq, bq);
                  dot_seg<16>(acc, hbase, WLe + 64*8, rq, bq); break;
          case 2: dot_seg<40>(acc, hbase + 16*64,  WLe + 80*8,  rq, bq); break;
          case 3: dot_seg<40>(acc, hbase + 56*64,  WLe + 120*8, rq, bq); break;
          case 4: dot_seg<40>(acc, hbase + 96*64,  WLe + 160*8, rq, bq); break;
          case 5: dot_seg<40>(acc, hbase + 136*64, WLe + 200*8, rq, bq); break;
          case 6: dot_seg<40>(acc, hbase + 176*64, WLe + 240*8, rq, bq); break;
          default:dot_seg<40>(acc, hbase + 216*64, WLe + 280*8, rq, bq); break;
        }
      } else {
        const float* ib = ws + H1T_ + (size_t)tt * 512 * 64;
        switch (q) {
          case 0: dot_seg<96>(acc, ib,          WLe,         rq, bq); break;
          case 1: dot_seg<96>(acc, ib + 96*64,  WLe + 96*8,  rq, bq); break;
          case 2: dot_seg<96>(acc, ib + 192*64, WLe + 192*8, rq, bq); break;
          case 3: dot_seg<96>(acc, ib + 288*64, WLe + 288*8, rq, bq); break;
          case 4: dot_seg<96>(acc, ib + 384*64, WLe + 384*8, rq, bq); break;
          case 5: dot_seg<32>(acc, ib + 480*64, WLe + 480*8, rq, bq);
                  dot_seg<64>(acc, hbase, WLe + 512*8, rq, bq); break;
          case 6: dot_seg<96>(acc, hbase + 64*64,  WLe + 576*8, rq, bq); break;
          default:dot_seg<96>(acc, hbase + 160*64, WLe + 672*8, rq, bq); break;
        }
      }
#pragma unroll
      for (int r = 0; r < 4; ++r)
        *(float2*)&REDe[((q * 8 + rq * 4 + r) * 64) + 2 * bq] = make_float2(acc[r][0], acc[r][1]);
      __syncthreads();
      if (tid < 128) {
        int b = tid & 63, u = tid >> 6;
        float g4[4];
#pragma unroll
        for (int g = 0; g < 4; ++g) {
          int slot = g * 2 + u;
          float s = BIe[slot];
#pragma unroll
          for (int qq = 0; qq < 8; ++qq) s += REDe[(qq * 8 + slot) * 64 + b];
          g4[g] = s;
        }
        float iv = sigm(g4[0]), fv = sigm(g4[1]), gv = tanhf(g4[2]), ov = sigm(g4[3]);
        int j = u0 + u, kk = d * 256 + j;
        float c1 = fv * cReg + iv * gv;
        cReg = c1;
        float h1 = ov * tanhf(c1);
        hReg = h1;
        ast(ws + HST_ + ((size_t)(d * 2 + nxt) * 256 + j) * 64 + b, h1);
        if (layer == 0) ws[H1T_ + ((size_t)tt * 512 + kk) * 64 + b] = h1;
        else            ws[ENC_ + ((size_t)b * 512 + kk) * 512 + tt] = h1;
      }
      dbar(dirbar, wgl);
    }
    if (layer == 0) {
      if (tid < 128) {
        int b = tid & 63, u = tid >> 6;
        ast(ws + HST_ + ((size_t)(d * 2 + 0) * 256 + u0 + u) * 64 + b, 0.f);
        ast(ws + HST_ + ((size_t)(d * 2 + 1) * 256 + u0 + u) * 64 + b, 0.f);
        cReg = 0.f;
      }
    }
  }

  // ---------- decoder init: publish h0/c0; load decoder weights (bf16 LDS) ----------
  if (tid < 128) {
    int b = tid & 63, u = tid >> 6;
    int k = wg * 2 + u;
    ast(ws + HDT_ + (size_t)k * 64 + b, hReg);
    ast(ws + HDB_ + (size_t)b * 512 + k, hReg);
    ast(ws + CDB_ + (size_t)b * 512 + k, cReg);
  }
  fill_wld(wld, BId, Wihd, Whhd, bihd, bhhd, 1088, 512, 512, wg * 2, 1600);
  fullbar(bar, wg);   // ENC bulk stores + h0/c0 visible

  const float bp0 = bp[0];
  const int ab = wg >> 2;                 // batch owned for attention
  const int j4 = wg & 3;                  // s-quarter
  unsigned* mb = bar + 4096 + ab * 64;

  // ---------- load ENC slab -> LDS bf16, XOR-swizzled [512 k][64 dw] ----------
  {
    const int dc = tid & 63, k0 = tid >> 6;
    const float* src = ws + ENC_ + (size_t)ab * 262144 + (size_t)j4 * 128;
#pragma unroll 4
    for (int i = 0; i < 64; ++i) {
      int k = k0 + i * 8;
      float2 e = *(const float2*)(src + (size_t)k * 512 + dc * 2);
      unsigned pk = (unsigned)f2bf(e.x) | ((unsigned)f2bf(e.y) << 16);
      encl[k * 64 + (dc ^ (k & 31))] = pk;
    }
  }
  __syncthreads();

  for (int t = 0; t < 512; ++t) {
    const int cur = t & 1, nxt = cur ^ 1;

    // ===== Phase A: h,c -> LDS; projection; scores from LDS slab =====
    r4[tid]       = ws[HDB_ + (size_t)cur * 32768 + (size_t)ab * 512 + tid];  // HB
    // CB at r4+512 loaded below to keep one store per thread each
    r4[512 + tid > 1023 ? 0 : 512 + tid] = r4[512 + tid > 1023 ? 0 : 512 + tid]; // (no-op guard)
    __syncthreads();
    // actually load CB now (separate pass keeps code simple)
    {
      float cv = ws[CDB_ + (size_t)ab * 512 + tid];
      r4[512 + tid] = cv;
    }
    __syncthreads();

    float pv = r4[tid] * Wp[tid];
#pragma unroll
    for (int o = 1; o <= 32; o <<= 1) pv += __shfl_xor(pv, o);
    if (lane == 0) PRJ[w] = pv;

    const int sp = tid & 63, wv = tid >> 6;
    float sh0 = 0.f, sh1 = 0.f, sc0 = 0.f, sc1 = 0.f;
#pragma unroll 8
    for (int kk = 0; kk < 64; ++kk) {
      int k = wv * 64 + kk;
      unsigned uv = encl[k * 64 + (sp ^ (k & 31))];
      float e0 = bf2f((unsigned short)(uv & 0xffffu));
      float e1 = bf2f((unsigned short)(uv >> 16));
      float hk = r4[k], ck = r4[512 + k];
      sh0 = fmaf(e0, hk, sh0); sh1 = fmaf(e1, hk, sh1);
      sc0 = fmaf(e0, ck, sc0); sc1 = fmaf(e1, ck, sc1);
    }
    __syncthreads();   // HB/CB dead; r4 becomes reduce scratch
    *(float2*)&r4[wv * 128 + sp * 2] = make_float2(sh0, sh1);
    __syncthreads();
    if (tid < 128) {
      float th = 0.f;
#pragma unroll
      for (int ww = 0; ww < 8; ++ww) th += r4[ww * 128 + tid];
      ast(ws + SCO_ + ((size_t)ab * 2 + 0) * 512 + j4 * 128 + tid, th);
    }
    __syncthreads();
    *(float2*)&r4[wv * 128 + sp * 2] = make_float2(sc0, sc1);
    __syncthreads();
    if (tid < 128) {
      float tc = 0.f;
#pragma unroll
      for (int ww = 0; ww < 8; ++ww) tc += r4[ww * 128 + tid];
      ast(ws + SCO_ + ((size_t)ab * 2 + 1) * 512 + j4 * 128 + tid, tc);
      if (tid == 0 && j4 == 0 && t > 0) {
        float v = bp0;
#pragma unroll
        for (int ww = 0; ww < 8; ++ww) v += PRJ[ww];
        out[(size_t)ab * 512 + (t - 1)] = v;
      }
    }
    mbar4(mb);

    // ===== softmax over full 512 (replicated); keep only my quarter's weights =====
    {
      float vh = ws[SCO_ + ((size_t)ab * 2 + 0) * 512 + tid];
      float vc = ws[SCO_ + ((size_t)ab * 2 + 1) * 512 + tid];
      float mh = vh, mc = vc;
#pragma unroll
      for (int o = 1; o <= 32; o <<= 1) { mh = fmaxf(mh, __shfl_xor(mh, o)); mc = fmaxf(mc, __shfl_xor(mc, o)); }
      if (lane == 0) { SMX[w] = mh; SMX[8 + w] = mc; }
      __syncthreads();
      mh = SMX[0]; mc = SMX[8];
#pragma unroll
      for (int ww = 1; ww < 8; ++ww) { mh = fmaxf(mh, SMX[ww]); mc = fmaxf(mc, SMX[8 + ww]); }
      float eh = expf(vh - mh), ec = expf(vc - mc);
      float zh = eh, zc = ec;
#pragma unroll
      for (int o = 1; o <= 32; o <<= 1) { zh += __shfl_xor(zh, o); zc += __shfl_xor(zc, o); }
      if (lane == 0) { SMX[16 + w] = zh; SMX[24 + w] = zc; }
      __syncthreads();
      zh = 0.f; zc = 0.f;
#pragma unroll
      for (int ww = 0; ww < 8; ++ww) { zh += SMX[16 + ww]; zc += SMX[24 + ww]; }
      if ((tid >> 7) == j4) {        // my s-quarter -> WHq/WCq in r4[0..255]
        int sl = tid & 127;
        r4[sl]       = eh / zh;
        r4[128 + sl] = ec / zc;
      }
    }
    __syncthreads();

    // ===== partial ctx over MY s-quarter, all k (thread = k) =====
    {
      const int k = tid;
      float ph = 0.f, pc = 0.f;
#pragma unroll 8
      for (int dc = 0; dc < 64; ++dc) {
        unsigned uv = encl[k * 64 + (dc ^ (k & 31))];
        float e0 = bf2f((unsigned short)(uv & 0xffffu));
        float e1 = bf2f((unsigned short)(uv >> 16));
        float wh0 = r4[2 * dc], wh1 = r4[2 * dc + 1];
        float wc0 = r4[128 + 2 * dc], wc1 = r4[128 + 2 * dc + 1];
        ph += e0 * wh0 + e1 * wh1;
        pc += e0 * wc0 + e1 * wc1;
      }
      ast(ws + PART_ + (((size_t)ab * 4 + j4) * 512 + k) * 2 + 0, ph);
      ast(ws + PART_ + (((size_t)ab * 4 + j4) * 512 + k) * 2 + 1, pc);
    }
    mbar4(mb);

    // ===== reduce 4 partials -> final ctx[k][b] (WG covers k-quarter j4) =====
    if (tid < 256) {
      int kl = tid >> 1, hc = tid & 1;
      int k = j4 * 128 + kl;
      float v = 0.f;
#pragma unroll
      for (int sq = 0; sq < 4; ++sq)
        v += ws[PART_ + (((size_t)ab * 4 + sq) * 512 + k) * 2 + hc];
      ast(ws + CTXD_ + ((size_t)hc * 512 + k) * 64 + ab, v);
    }
    gbar(bar, wg);

    // ===== Phase C: gate GEMM (K=1600, bf16 weights LDS, LDS-atomic reduce) =====
    r4[tid] = 0.f;   // GACC[8 slots][64 b] in r4[0..511]
    __syncthreads();
    {
      float acc[4][2] = {{0.f,0.f},{0.f,0.f},{0.f,0.f},{0.f,0.f}};
      const float* xb  = ws + XT_  + (size_t)t * 4096;
      const float* ctx = ws + CTXD_;
      const float* hdb = ws + HDT_ + (size_t)cur * 32768;
      switch (q) {
        case 0: dotw<64>(acc, xb, wld, rq, bq);
                dotw<136>(acc, ctx, wld + 64*8, rq, bq); break;
        case 1: dotw<200>(acc, ctx + 136*64, wld + 200*8, rq, bq); break;
        case 2: dotw<200>(acc, ctx + 336*64, wld + 400*8, rq, bq); break;
        case 3: dotw<200>(acc, ctx + 536*64, wld + 600*8, rq, bq); break;
        case 4: dotw<200>(acc, ctx + 736*64, wld + 800*8, rq, bq); break;
        case 5: dotw<88>(acc, ctx + 936*64, wld + 1000*8, rq, bq);
                dotw<112>(acc, hdb, wld + 1088*8, rq, bq); break;
        case 6: dotw<200>(acc, hdb + 112*64, wld + 1200*8, rq, bq); break;
        default:dotw<200>(acc, hdb + 312*64, wld + 1400*8, rq, bq); break;
      }
#pragma unroll
      for (int r = 0; r < 4; ++r) {
        atomicAdd(&r4[(rq * 4 + r) * 64 + 2 * bq],     acc[r][0]);
        atomicAdd(&r4[(rq * 4 + r) * 64 + 2 * bq + 1], acc[r][1]);
      }
      __syncthreads();
      if (tid < 128) {
        int b = tid & 63, u = tid >> 6;
        float g4[4];
#pragma unroll
        for (int g = 0; g < 4; ++g)
          g4[g] = BId[g * 2 + u] + r4[(g * 2 + u) * 64 + b];
        float iv = sigm(g4[0]), fv = sigm(g4[1]), gv = tanhf(g4[2]), ov = sigm(g4[3]);
        int k = wg * 2 + u;
        float c1 = fv * cReg + iv * gv;
        cReg = c1;
        float h1 = ov * tanhf(c1);
        ast(ws + CDB_ + (size_t)b * 512 + k, c1);
        ast(ws + HDT_ + (size_t)nxt * 32768 + (size_t)k * 64 + b, h1);
        ast(ws + HDB_ + (size_t)nxt * 32768 + (size_t)b * 512 + k, h1);
      }
    }
    gbar(bar, wg);
  }

  // ---------- epilogue: out[b][511] from final h (buf 0) ----------
  if (j4 == 0) {
    r4[tid] = ws[HDB_ + (size_t)ab * 512 + tid];
    __syncthreads();
    float pv = r4[tid] * Wp[tid];
#pragma unroll
    for (int o = 1; o <= 32; o <<= 1) pv += __shfl_xor(pv, o);
    if (lane == 0) PRJ[w] = pv;
    __syncthreads();
    if (tid == 0) {
      float v = bp0;
#pragma unroll
      for (int ww = 0; ww < 8; ++ww) v += PRJ[ww];
      out[(size_t)ab * 512 + 511] = v;
    }
  }
}

extern "C" void kernel_launch(void* const* d_in, const int* in_sizes, int n_in,
                              void* d_out, int out_size, void* d_ws, size_t ws_size,
                              hipStream_t stream) {
  const float* x    = (const float*)d_in[0];
  const float* Wih0 = (const float*)d_in[1];
  const float* Whh0 = (const float*)d_in[2];
  const float* bih0 = (const float*)d_in[3];
  const float* bhh0 = (const float*)d_in[4];
  const float* Wih1 = (const float*)d_in[5];
  const float* Whh1 = (const float*)d_in[6];
  const float* bih1 = (const float*)d_in[7];
  const float* bhh1 = (const float*)d_in[8];
  const float* Wihd = (const float*)d_in[9];
  const float* Whhd = (const float*)d_in[10];
  const float* bihd = (const float*)d_in[11];
  const float* bhhd = (const float*)d_in[12];
  const float* Wp   = (const float*)d_in[13];
  const float* bp   = (const float*)d_in[14];
  float* out = (float*)d_out;
  float* ws  = (float*)d_ws;
  (void)ws_size; (void)n_in; (void)in_sizes;

  hipMemsetAsync(d_ws, 0, 8192 * 4, stream);
  hipMemsetAsync(d_out, 0, (size_t)out_size * sizeof(float), stream);

  hipFuncSetAttribute((const void*)seq2seq_ker,
                      hipFuncAttributeMaxDynamicSharedMemorySize, SMEM_BYTES);

  hipLaunchKernelGGL(seq2seq_ker, dim3(NWG), dim3(NT), SMEM_BYTES, stream,
                     x, Wih0, Whh0, bih0, bhh0, Wih1, Whh1, bih1, bhh1,
                     Wihd, Whhd, bihd, bhhd, Wp, bp, out, ws);
}

// Round 6
// 38220.486 us; speedup vs baseline: 2.9015x; 1.3801x over previous
//
#include <hip/hip_runtime.h>
#include <cmath>

#define NWG 256
#define NT  512

typedef unsigned long long u64;
typedef unsigned short u16;
typedef unsigned int u32;

// ---------------- workspace layout (float offsets) ----------------
static constexpr size_t XT_   = 8192;                       // f32 [t][k][b]      2,097,152
static constexpr size_t XB_   = XT_   + 2097152;            // u16 [t][b][64]     (1,048,576 fl)
static constexpr size_t H1T_  = XB_   + 1048576;            // f32 [t][k][b]      16,777,216
static constexpr size_t ENCQ_ = H1T_  + 16777216;           // u16 [b][512][512]  (8,388,608 fl)
static constexpr size_t HST_  = ENCQ_ + 8388608;            // f32 [d][buf][j][b] 65,536
static constexpr size_t HF_   = HST_  + 65536;              // f32 [512][64]
static constexpr size_t CF_   = HF_   + 32768;              // f32 [512][64]
static constexpr size_t HB_   = CF_   + 32768;              // u16 [2][64][512]   (32,768 fl)
static constexpr size_t CTXB_ = HB_   + 32768;              // u16 [64][1024]     (32,768 fl)
static constexpr size_t SCP_  = CTXB_ + 32768;              // f32 [64][4][2][512] 262,144
static constexpr size_t PROJ_ = SCP_  + 262144;             // f32 [2][64][4]     512
static constexpr size_t WDQ_  = PROJ_ + 512;                // u16 [4][1600][512] (1,638,400 fl)
// end ~30.4M floats ~122 MB

// ---------------- LDS layout ----------------
// decoder (float offsets): slab32 u32[32768] @0 (128KB); then f32 regions:
static constexpr int ACT_F = 32768;   // act[1600]
static constexpr int WH_F  = 34368;   // wh[512]
static constexpr int WC_F  = 34880;   // wc[512]
static constexpr int RED_F = 35392;   // red[2048]
static constexpr int GT_F  = 37440;   // gates[512]
static constexpr int BI_F  = 37952;   // bias[512]
static constexpr int HL_F  = 38464;   // h_loc[128]
static constexpr int CL_F  = 38592;   // c_loc[128]
static constexpr int WPS_F = 38720;   // wp slice[128]
static constexpr int CXL_F = 38848;   // ctx_loc[256]
static constexpr int SMX_F = 39104;   // smx[64]
static constexpr int SMEM_F = 39168;  // 156,672 B
// encoder aliases (time-disjoint): WLe@0 [768*8], REDe@6144 [4096], BIe@10240 [8]
static constexpr int WLE_F = 0, REDE_F = 6144, BIE_F = 10240;

__device__ __forceinline__ float sigm(float v) { return 1.f / (1.f + expf(-v)); }
__device__ __forceinline__ u16 f2bf(float f) {
  u32 u = __float_as_uint(f);
  u += 0x7fffu + ((u >> 16) & 1u);
  return (u16)(u >> 16);
}
__device__ __forceinline__ float bf2f(u16 h) { return __uint_as_float((u32)h << 16); }
__device__ __forceinline__ u64 pk4(const float* p) {
  return (u64)f2bf(p[0]) | ((u64)f2bf(p[1]) << 16) | ((u64)f2bf(p[2]) << 32) | ((u64)f2bf(p[3]) << 48);
}

__device__ __forceinline__ unsigned uld(unsigned* p) {
  return __hip_atomic_load(p, __ATOMIC_RELAXED, __HIP_MEMORY_SCOPE_AGENT);
}
__device__ __forceinline__ unsigned uadd(unsigned* p) {
  return __hip_atomic_fetch_add(p, 1u, __ATOMIC_RELAXED, __HIP_MEMORY_SCOPE_AGENT);
}
__device__ __forceinline__ float ald(const float* p) {
  return __hip_atomic_load(p, __ATOMIC_RELAXED, __HIP_MEMORY_SCOPE_AGENT);
}
__device__ __forceinline__ void ast(float* p, float v) {
  __hip_atomic_store(p, v, __ATOMIC_RELAXED, __HIP_MEMORY_SCOPE_AGENT);
}
__device__ __forceinline__ u64 a64ld(const u64* p) {
  return __hip_atomic_load(p, __ATOMIC_RELAXED, __HIP_MEMORY_SCOPE_AGENT);
}
__device__ __forceinline__ void a64st(u64* p, u64 v) {
  __hip_atomic_store(p, v, __ATOMIC_RELAXED, __HIP_MEMORY_SCOPE_AGENT);
}
__device__ __forceinline__ void acqf() { __builtin_amdgcn_fence(__ATOMIC_ACQUIRE, "agent"); }
__device__ __forceinline__ void relf() { __builtin_amdgcn_fence(__ATOMIC_RELEASE, "agent"); }

// full-grid barrier WITH fences (phase boundaries only): monotonic 3-level tree
__device__ __forceinline__ void fullbar(unsigned* bar, int wg) {
  __syncthreads();
  if (threadIdx.x == 0) {
    relf();
    unsigned g = uld(bar);
    if (((uadd(&bar[32 + (wg >> 3) * 32]) + 1) & 7) == 0)
      if (((uadd(&bar[1056 + (wg >> 6) * 32]) + 1) & 7) == 0)
        if (((uadd(&bar[1184]) + 1) & 3) == 0)
          uadd(bar);
    while (uld(bar) == g) __builtin_amdgcn_s_sleep(2);
    acqf();
  }
  __syncthreads();
}

// direction-local 128-WG relaxed barrier, fence-free
__device__ __forceinline__ void dbar(unsigned* base, int wgl) {
  __syncthreads();
  if (threadIdx.x == 0) {
    unsigned g = uld(base);
    if (((uadd(&base[32 + (wgl >> 3) * 32]) + 1) & 7) == 0)
      if (((uadd(&base[544]) + 1) & 15) == 0)
        uadd(base);
    while (uld(base) == g) __builtin_amdgcn_s_sleep(1);
  }
  __syncthreads();
}

// 4-WG relaxed minibar, fence-free
__device__ __forceinline__ void mbar4(unsigned* base) {
  __syncthreads();
  if (threadIdx.x == 0) {
    unsigned g = uld(base);
    if (((uadd(&base[32]) + 1) & 3) == 0) uadd(base);
    while (uld(base) == g) __builtin_amdgcn_s_sleep(1);
  }
  __syncthreads();
}

// encoder gate-GEMM K-segment, cached f32 activations
template<int N>
__device__ __forceinline__ void dot_seg(float (&acc)[4][2], const float* kb,
                                        const float* wl, int rq, int bq) {
#pragma unroll 16
  for (int i = 0; i < N; ++i) {
    float2 hv = *(const float2*)(kb + (size_t)i * 64 + 2 * bq);
    float4 wv = *(const float4*)(wl + i * 8 + rq * 4);
    acc[0][0] = fmaf(wv.x, hv.x, acc[0][0]); acc[0][1] = fmaf(wv.x, hv.y, acc[0][1]);
    acc[1][0] = fmaf(wv.y, hv.x, acc[1][0]); acc[1][1] = fmaf(wv.y, hv.y, acc[1][1]);
    acc[2][0] = fmaf(wv.z, hv.x, acc[2][0]); acc[2][1] = fmaf(wv.z, hv.y, acc[2][1]);
    acc[3][0] = fmaf(wv.w, hv.x, acc[3][0]); acc[3][1] = fmaf(wv.w, hv.y, acc[3][1]);
  }
}

// same, but activations via relaxed b64 agent-atomic loads (coherent h-state)
template<int N>
__device__ __forceinline__ void dot_at2(float (&acc)[4][2], const float* kb,
                                        const float* wl, int rq, int bq) {
#pragma unroll 16
  for (int i = 0; i < N; ++i) {
    u64 v = a64ld((const u64*)(kb + (size_t)i * 64 + 2 * bq));
    float h0 = __uint_as_float((u32)v);
    float h1 = __uint_as_float((u32)(v >> 32));
    float4 wv = *(const float4*)(wl + i * 8 + rq * 4);
    acc[0][0] = fmaf(wv.x, h0, acc[0][0]); acc[0][1] = fmaf(wv.x, h1, acc[0][1]);
    acc[1][0] = fmaf(wv.y, h0, acc[1][0]); acc[1][1] = fmaf(wv.y, h1, acc[1][1]);
    acc[2][0] = fmaf(wv.z, h0, acc[2][0]); acc[2][1] = fmaf(wv.z, h1, acc[2][1]);
    acc[3][0] = fmaf(wv.w, h0, acc[3][0]); acc[3][1] = fmaf(wv.w, h1, acc[3][1]);
  }
}

// encoder: this WG's 8 gate rows (2 units x 4 gates) into LDS f32, plus bias
__device__ void fill_wl(float* WLs, float* BIs,
                        const float* Wih, const float* Whh,
                        const float* bih, const float* bhh,
                        int KI, int KH, int gstride, int u0, int K) {
  for (int idx = threadIdx.x; idx < K * 8; idx += NT) {
    int k = idx >> 3, slot = idx & 7;
    int row = (slot >> 1) * gstride + u0 + (slot & 1);
    WLs[k * 8 + slot] = (k < KI) ? Wih[(size_t)row * KI + k]
                                 : Whh[(size_t)row * KH + (k - KI)];
  }
  if (threadIdx.x < 8) {
    int row = ((int)threadIdx.x >> 1) * gstride + u0 + ((int)threadIdx.x & 1);
    BIs[threadIdx.x] = bih[row] + bhh[row];
  }
  __syncthreads();
}

extern "C" __global__ void __launch_bounds__(NT, 1)
seq2seq_ker(const float* __restrict__ x,
            const float* __restrict__ Wih0, const float* __restrict__ Whh0,
            const float* __restrict__ bih0, const float* __restrict__ bhh0,
            const float* __restrict__ Wih1, const float* __restrict__ Whh1,
            const float* __restrict__ bih1, const float* __restrict__ bhh1,
            const float* __restrict__ Wihd, const float* __restrict__ Whhd,
            const float* __restrict__ bihd, const float* __restrict__ bhhd,
            const float* __restrict__ Wp,   const float* __restrict__ bp,
            float* out, float* ws) {
  extern __shared__ float smem[];
  unsigned* bar = (unsigned*)ws;
  const int tid = threadIdx.x;
  const int wg  = blockIdx.x;
  const int gtid = wg * NT + tid;
  const int lane = tid & 63, q = tid >> 6;
  const int rq = lane & 1, bq = lane >> 1;

  // ---------- prologue: XT (f32 [t][k][b]), XB (bf16 [t][b][k]), WDQ, zero HST ----------
  for (size_t i = gtid; i < (size_t)512 * 64 * 64; i += (size_t)NWG * NT) {
    int k = (int)(i & 63), tt2 = (int)((i >> 6) & 511), bb = (int)(i >> 15);
    float v = x[i];
    ws[XT_ + (size_t)tt2 * 4096 + k * 64 + bb] = v;
    ((u16*)(ws + XB_))[((size_t)tt2 * 64 + bb) * 64 + k] = f2bf(v);
  }
  for (size_t idx = gtid; idx < (size_t)4 * 1600 * 128; idx += (size_t)NWG * NT) {
    int p = (int)(idx & 127);
    size_t rem = idx >> 7;
    int k = (int)(rem % 1600);
    int jq = (int)(rem / 1600);
    u64 v = 0;
#pragma unroll
    for (int j = 0; j < 4; ++j) {
      int r = 4 * p + j;
      int row = (r >> 7) * 512 + jq * 128 + (r & 127);
      float wv = (k < 1088) ? Wihd[(size_t)row * 1088 + k]
                            : Whhd[(size_t)row * 512 + (k - 1088)];
      v |= (u64)f2bf(wv) << (16 * j);
    }
    ((u64*)((u16*)(ws + WDQ_)))[(size_t)jq * 1600 * 128 + (size_t)k * 128 + p] = v;
  }
  if (gtid < 65536) ast(ws + HST_ + gtid, 0.f);

  // ---------- encoder: 2 layers ----------
  const int d  = wg >> 7;
  const int u0 = (wg & 127) * 2;
  const int wgl = wg & 127;
  unsigned* dirbar = bar + 2048 + d * 1024;
  float* WLe = smem + WLE_F;
  float* REDe = smem + REDE_F;
  float* BIe = smem + BIE_F;

  float cReg = 0.f, hReg = 0.f;

  for (int layer = 0; layer < 2; ++layer) {
    if (layer == 0)
      fill_wl(WLe, BIe, Wih0 + (size_t)d * 1024 * 64,  Whh0 + (size_t)d * 1024 * 256,
              bih0 + d * 1024, bhh0 + d * 1024, 64, 256, 256, u0, 320);
    else
      fill_wl(WLe, BIe, Wih1 + (size_t)d * 1024 * 512, Whh1 + (size_t)d * 1024 * 256,
              bih1 + d * 1024, bhh1 + d * 1024, 512, 256, 256, u0, 768);
    fullbar(bar, wg);   // bulk data (XT/XB/WDQ/H1T) + zeroed state visible

    for (int t = 0; t < 512; ++t) {
      const int cur = t & 1, nxt = cur ^ 1;
      const int tt = d ? (511 - t) : t;
      float acc[4][2] = {{0.f,0.f},{0.f,0.f},{0.f,0.f},{0.f,0.f}};
      const float* hbase = ws + HST_ + ((size_t)(d * 2 + cur) * 256) * 64;
      if (layer == 0) {
        const float* xb = ws + XT_ + (size_t)tt * 4096;
        switch (q) {
          case 0: dot_seg<40>(acc, xb, WLe, rq, bq); break;
          case 1: dot_seg<24>(acc, xb + 40*64, WLe + 40*8, rq, bq);
                  dot_at2<16>(acc, hbase, WLe + 64*8, rq, bq); break;
          case 2: dot_at2<40>(acc, hbase + 16*64,  WLe + 80*8,  rq, bq); break;
          case 3: dot_at2<40>(acc, hbase + 56*64,  WLe + 120*8, rq, bq); break;
          case 4: dot_at2<40>(acc, hbase + 96*64,  WLe + 160*8, rq, bq); break;
          case 5: dot_at2<40>(acc, hbase + 136*64, WLe + 200*8, rq, bq); break;
          case 6: dot_at2<40>(acc, hbase + 176*64, WLe + 240*8, rq, bq); break;
          default:dot_at2<40>(acc, hbase + 216*64, WLe + 280*8, rq, bq); break;
        }
      } else {
        const float* ib = ws + H1T_ + (size_t)tt * 512 * 64;
        switch (q) {
          case 0: dot_seg<96>(acc, ib,          WLe,         rq, bq); break;
          case 1: dot_seg<96>(acc, ib + 96*64,  WLe + 96*8,  rq, bq); break;
          case 2: dot_seg<96>(acc, ib + 192*64, WLe + 192*8, rq, bq); break;
          case 3: dot_seg<96>(acc, ib + 288*64, WLe + 288*8, rq, bq); break;
          case 4: dot_seg<96>(acc, ib + 384*64, WLe + 384*8, rq, bq); break;
          case 5: dot_seg<32>(acc, ib + 480*64, WLe + 480*8, rq, bq);
                  dot_at2<64>(acc, hbase, WLe + 512*8, rq, bq); break;
          case 6: dot_at2<96>(acc, hbase + 64*64,  WLe + 576*8, rq, bq); break;
          default:dot_at2<96>(acc, hbase + 160*64, WLe + 672*8, rq, bq); break;
        }
      }
#pragma unroll
      for (int r = 0; r < 4; ++r)
        *(float2*)&REDe[((q * 8 + rq * 4 + r) * 64) + 2 * bq] = make_float2(acc[r][0], acc[r][1]);
      __syncthreads();
      if (tid < 128) {
        int b = tid & 63, u = tid >> 6;
        float g4[4];
#pragma unroll
        for (int g = 0; g < 4; ++g) {
          int slot = g * 2 + u;
          float s = BIe[slot];
#pragma unroll
          for (int qq = 0; qq < 8; ++qq) s += REDe[(qq * 8 + slot) * 64 + b];
          g4[g] = s;
        }
        float iv = sigm(g4[0]), fv = sigm(g4[1]), gv = tanhf(g4[2]), ov = sigm(g4[3]);
        int j = u0 + u, kk = d * 256 + j;
        float c1 = fv * cReg + iv * gv;
        cReg = c1;
        float h1 = ov * tanhf(c1);
        hReg = h1;
        ast(ws + HST_ + ((size_t)(d * 2 + nxt) * 256 + j) * 64 + b, h1);
        if (layer == 0) ws[H1T_ + ((size_t)tt * 512 + kk) * 64 + b] = h1;
        else            ((u16*)(ws + ENCQ_))[((size_t)b * 512 + kk) * 512 + tt] = f2bf(h1);
      }
      dbar(dirbar, wgl);
    }
    if (layer == 0) {
      if (tid < 128) {
        int b = tid & 63, u = tid >> 6;
        ast(ws + HST_ + ((size_t)(d * 2 + 0) * 256 + u0 + u) * 64 + b, 0.f);
        ast(ws + HST_ + ((size_t)(d * 2 + 1) * 256 + u0 + u) * 64 + b, 0.f);
        cReg = 0.f;
      }
    }
  }

  // publish final h/c (f32) for decoder init
  if (tid < 128) {
    int b = tid & 63, u = tid >> 6;
    int kd = d * 256 + u0 + u;
    ast(ws + HF_ + (size_t)kd * 64 + b, hReg);
    ast(ws + CF_ + (size_t)kd * 64 + b, cReg);
  }
  fullbar(bar, wg);   // ENCQ + HF/CF visible

  // ---------- decoder: 64 independent 4-WG clusters ----------
  const int b  = wg >> 2;     // batch
  const int j4 = wg & 3;      // k-quarter (and XCD affinity for weight quarter)
  unsigned* mb = bar + 4096 + b * 64;

  u32* slab32 = (u32*)smem;                 // [128 u][256 c] swizzled c^(u&31)
  float* act = smem + ACT_F;
  float* wh  = smem + WH_F;
  float* wc  = smem + WC_F;
  float* red = smem + RED_F;
  float* gt  = smem + GT_F;
  float* bi  = smem + BI_F;
  float* h_loc = smem + HL_F;
  float* c_loc = smem + CL_F;
  float* wps = smem + WPS_F;
  float* cxl = smem + CXL_F;
  float* smx = smem + SMX_F;

  // load slab (swizzled), bias, Wp slice, h0/c0
  {
    const u32* src = (const u32*)((const u16*)(ws + ENCQ_) + ((size_t)b * 512 + j4 * 128) * 512);
    for (int i = tid; i < 32768; i += NT) {
      int u = i >> 8, c = i & 255;
      slab32[u * 256 + (c ^ (u & 31))] = src[i];
    }
  }
  for (int r = tid; r < 512; r += NT) {
    int row = (r >> 7) * 512 + j4 * 128 + (r & 127);
    bi[r] = bihd[row] + bhhd[row];
  }
  if (tid < 128) {
    wps[tid] = Wp[j4 * 128 + tid];
    h_loc[tid] = ald(ws + HF_ + (size_t)(j4 * 128 + tid) * 64 + b);
    c_loc[tid] = ald(ws + CF_ + (size_t)(j4 * 128 + tid) * 64 + b);
  }
  __syncthreads();
  if (tid < 32) {  // publish h0 -> HB buf 0
    u64 v = pk4(&h_loc[4 * tid]);
    a64st((u64*)((u16*)(ws + HB_) + ((size_t)0 * 64 + b) * 512 + j4 * 128) + tid, v);
  }
  const float bp0 = bp[0];

  for (int t = 0; t < 512; ++t) {
    // ===== score partials for my k-slice (fully local h,c) =====
    {
      int s = tid, c = s >> 1, sh = (s & 1) * 16;
      float ah = 0.f, ac = 0.f;
#pragma unroll 8
      for (int u = 0; u < 128; ++u) {
        u32 pv = slab32[u * 256 + (c ^ (u & 31))];
        float e = bf2f((u16)(pv >> sh));
        ah = fmaf(e, h_loc[u], ah);
        ac = fmaf(e, c_loc[u], ac);
      }
      ast(ws + SCP_ + (((size_t)b * 4 + j4) * 2 + 0) * 512 + s, ah);
      ast(ws + SCP_ + (((size_t)b * 4 + j4) * 2 + 1) * 512 + s, ac);
    }
    mbar4(mb);

    // ===== reduce partials + replicated softmax over 512 =====
    {
      int s = tid;
      float sh = 0.f, sc = 0.f;
#pragma unroll
      for (int jj = 0; jj < 4; ++jj) {
        sh += ald(ws + SCP_ + (((size_t)b * 4 + jj) * 2 + 0) * 512 + s);
        sc += ald(ws + SCP_ + (((size_t)b * 4 + jj) * 2 + 1) * 512 + s);
      }
      float mh = sh, mc = sc;
#pragma unroll
      for (int o = 1; o <= 32; o <<= 1) { mh = fmaxf(mh, __shfl_xor(mh, o)); mc = fmaxf(mc, __shfl_xor(mc, o)); }
      if (lane == 0) { smx[q] = mh; smx[8 + q] = mc; }
      __syncthreads();
      mh = smx[0]; mc = smx[8];
#pragma unroll
      for (int ww = 1; ww < 8; ++ww) { mh = fmaxf(mh, smx[ww]); mc = fmaxf(mc, smx[8 + ww]); }
      float eh = expf(sh - mh), ec = expf(sc - mc);
      float zh = eh, zc = ec;
#pragma unroll
      for (int o = 1; o <= 32; o <<= 1) { zh += __shfl_xor(zh, o); zc += __shfl_xor(zc, o); }
      if (lane == 0) { smx[16 + q] = zh; smx[24 + q] = zc; }
      __syncthreads();
      zh = 0.f; zc = 0.f;
#pragma unroll
      for (int ww = 0; ww < 8; ++ww) { zh += smx[16 + ww]; zc += smx[24 + ww]; }
      wh[s] = eh / zh;
      wc[s] = ec / zc;
    }
    __syncthreads();

    // ===== ctx for my k-slice over all s (local) =====
    {
      int u = tid & 127, sq = tid >> 7, kx = u & 31;
      float ch = 0.f, cc = 0.f;
#pragma unroll 8
      for (int i = 0; i < 64; ++i) {
        int c = sq * 64 + i;
        u32 pv = slab32[u * 256 + (c ^ kx)];
        float e0 = bf2f((u16)pv), e1 = bf2f((u16)(pv >> 16));
        int s = 2 * c;
        ch += e0 * wh[s] + e1 * wh[s + 1];
        cc += e0 * wc[s] + e1 * wc[s + 1];
      }
      red[tid * 2] = ch;
      red[tid * 2 + 1] = cc;
    }
    __syncthreads();
    if (tid < 256) {
      int u = tid >> 1, hc = tid & 1;
      float v = red[(0 * 128 + u) * 2 + hc] + red[(1 * 128 + u) * 2 + hc]
              + red[(2 * 128 + u) * 2 + hc] + red[(3 * 128 + u) * 2 + hc];
      cxl[hc * 128 + u] = v;
    }
    __syncthreads();
    if (tid < 64) {  // publish ctx slice (bf16 packed)
      int i = tid & 31, hc = tid >> 5;
      u64 v = pk4(&cxl[hc * 128 + 4 * i]);
      a64st((u64*)((u16*)(ws + CTXB_) + (size_t)b * 1024 + hc * 512 + j4 * 128) + i, v);
    }
    mbar4(mb);

    // ===== stage act = [XB(t) | CTXB | HB(buf t&1)] ; out projection =====
    if (tid < 400) {
      u64 v;
      if (tid < 16)
        v = a64ld((const u64*)((const u16*)(ws + XB_) + ((size_t)t * 64 + b) * 64) + tid);
      else if (tid < 272)
        v = a64ld((const u64*)((const u16*)(ws + CTXB_) + (size_t)b * 1024) + (tid - 16));
      else
        v = a64ld((const u64*)((const u16*)(ws + HB_) + ((size_t)(t & 1) * 64 + b) * 512) + (tid - 272));
      float4 f = make_float4(bf2f((u16)v), bf2f((u16)(v >> 16)),
                             bf2f((u16)(v >> 32)), bf2f((u16)(v >> 48)));
      *(float4*)&act[4 * tid] = f;
    }
    if (j4 == 0 && tid == 448 && t > 0) {
      float v = bp0;
#pragma unroll
      for (int jj = 0; jj < 4; ++jj) v += ald(ws + PROJ_ + ((size_t)(t & 1) * 64 + b) * 4 + jj);
      out[(size_t)b * 512 + (t - 1)] = v;
    }
    __syncthreads();

    // ===== gate GEMM: 512 rows x K=1600, weights streamed from L2 (bf16) =====
    {
      int kq = tid >> 7, p = tid & 127;
      const u64* wq = (const u64*)((const u16*)(ws + WDQ_) + (size_t)j4 * 1600 * 512);
      float a0 = 0.f, a1 = 0.f, a2 = 0.f, a3 = 0.f;
      int k0 = kq * 400;
#pragma unroll 16
      for (int i = 0; i < 400; ++i) {
        int k = k0 + i;
        u64 wv = wq[(size_t)k * 128 + p];
        float a = act[k];
        a0 = fmaf(bf2f((u16)wv), a, a0);
        a1 = fmaf(bf2f((u16)(wv >> 16)), a, a1);
        a2 = fmaf(bf2f((u16)(wv >> 32)), a, a2);
        a3 = fmaf(bf2f((u16)(wv >> 48)), a, a3);
      }
      *(float4*)&red[tid * 4] = make_float4(a0, a1, a2, a3);
    }
    __syncthreads();
    {
      float g = bi[tid];
#pragma unroll
      for (int kq2 = 0; kq2 < 4; ++kq2) g += red[kq2 * 512 + tid];
      gt[tid] = g;
    }
    __syncthreads();
    if (tid < 128) {
      float iv = sigm(gt[tid]), fv = sigm(gt[128 + tid]);
      float gv = tanhf(gt[256 + tid]), ov = sigm(gt[384 + tid]);
      float c1 = fv * c_loc[tid] + iv * gv;
      c_loc[tid] = c1;
      h_loc[tid] = ov * tanhf(c1);
    }
    __syncthreads();
    // publish h(t+1) -> HB buf (t+1)&1 ; proj partial -> PROJ buf (t+1)&1
    if (tid < 32) {
      u64 v = pk4(&h_loc[4 * tid]);
      a64st((u64*)((u16*)(ws + HB_) + ((size_t)((t + 1) & 1) * 64 + b) * 512 + j4 * 128) + tid, v);
    }
    if (tid < 128) {
      float pv = h_loc[tid] * wps[tid];
#pragma unroll
      for (int o = 1; o <= 32; o <<= 1) pv += __shfl_xor(pv, o);
      if (lane == 0) smx[40 + (tid >> 6)] = pv;
    }
    __syncthreads();
    if (tid == 0)
      ast(ws + PROJ_ + ((size_t)((t + 1) & 1) * 64 + b) * 4 + j4, smx[40] + smx[41]);
  }

  // ---------- epilogue: out[b][511] ----------
  mbar4(mb);
  if (j4 == 0 && tid == 0) {
    float v = bp0;
#pragma unroll
    for (int jj = 0; jj < 4; ++jj) v += ald(ws + PROJ_ + ((size_t)0 * 64 + b) * 4 + jj);
    out[(size_t)b * 512 + 511] = v;
  }
}

extern "C" void kernel_launch(void* const* d_in, const int* in_sizes, int n_in,
                              void* d_out, int out_size, void* d_ws, size_t ws_size,
                              hipStream_t stream) {
  const float* x    = (const float*)d_in[0];
  const float* Wih0 = (const float*)d_in[1];
  const float* Whh0 = (const float*)d_in[2];
  const float* bih0 = (const float*)d_in[3];
  const float* bhh0 = (const float*)d_in[4];
  const float* Wih1 = (const float*)d_in[5];
  const float* Whh1 = (const float*)d_in[6];
  const float* bih1 = (const float*)d_in[7];
  const float* bhh1 = (const float*)d_in[8];
  const float* Wihd = (const float*)d_in[9];
  const float* Whhd = (const float*)d_in[10];
  const float* bihd = (const float*)d_in[11];
  const float* bhhd = (const float*)d_in[12];
  const float* Wp   = (const float*)d_in[13];
  const float* bp   = (const float*)d_in[14];
  float* out = (float*)d_out;
  float* ws  = (float*)d_ws;
  (void)ws_size; (void)n_in; (void)in_sizes; (void)out_size;

  // zero barrier counters (monotonic; reset each launch/replay)
  hipMemsetAsync(d_ws, 0, 32768, stream);

  hipFuncSetAttribute((const void*)seq2seq_ker,
                      hipFuncAttributeMaxDynamicSharedMemorySize, SMEM_F * 4);

  hipLaunchKernelGGL(seq2seq_ker, dim3(NWG), dim3(NT), SMEM_F * 4, stream,
                     x, Wih0, Whh0, bih0, bhh0, Wih1, Whh1, bih1, bhh1,
                     Wihd, Whhd, bihd, bhhd, Wp, bp, out, ws);
}